// Round 11
// baseline (388.945 us; speedup 1.0000x reference)
//
#include <hip/hip_runtime.h>

typedef _Float16 f16;
typedef f16 f16x8 __attribute__((ext_vector_type(8)));
typedef f16 f16x4 __attribute__((ext_vector_type(4)));
typedef short s16x8 __attribute__((ext_vector_type(8)));
typedef short s16x4 __attribute__((ext_vector_type(4)));
typedef float f32x4 __attribute__((ext_vector_type(4)));

#define MFMA16(a,b,c)  __builtin_amdgcn_mfma_f32_16x16x32_f16(a,b,c,0,0,0)
#define MFMAB16(a,b,c) __builtin_amdgcn_mfma_f32_16x16x32_bf16(a,b,c,0,0,0)

static constexpr int Bn = 8, Qn = 2048, Kn = 2048, Hn = 512;
static constexpr int Mn = Bn * Qn;           // 16384 flat rows

typedef __attribute__((address_space(1))) const unsigned int as1_uint;
typedef __attribute__((address_space(3))) unsigned int as3_uint;

__device__ __forceinline__ void gl_lds16(const void* g, void* l) {
    __builtin_amdgcn_global_load_lds((as1_uint*)g, (as3_uint*)l, 16, 0, 0);
}

__device__ __forceinline__ short bf16r(float x) {
    unsigned u = __builtin_bit_cast(unsigned, x);
    u += 0x7fffu + ((u >> 16) & 1u);
    return (short)(u >> 16);
}

// swizzle granule: 2-way (free) bank aliasing for ds_read_b128 column reads
__device__ __forceinline__ int swz(int row) { return (row >> 1) & 3; }

// ---------------------------------------------------------------------------
// prep_all: blocks 0..7 compact_mask; 8..1031 weight split/transpose;
// 1032 bias vectors.
// ---------------------------------------------------------------------------
__global__ __launch_bounds__(256) void prep_all(
    const int* __restrict__ mask, const float* __restrict__ Wk,
    const float* __restrict__ Wo, const float* __restrict__ bq,
    const float* __restrict__ bv, const float* __restrict__ bo,
    int* __restrict__ cidx, int* __restrict__ cnt,
    f16* __restrict__ Wk_h, f16* __restrict__ Wk_l, short* __restrict__ Wot,
    float* __restrict__ wvec, float* __restrict__ cvec)
{
    const int bid = blockIdx.x, t = threadIdx.x;
    if (bid < 8) {
        __shared__ int sums[256];
        int b = bid;
        int base = b * Kn + t * 8;
        int mv[8]; int s = 0;
        #pragma unroll
        for (int i = 0; i < 8; ++i) { mv[i] = (mask[base + i] == 0); s += mv[i]; }
        sums[t] = s;
        __syncthreads();
        for (int off = 1; off < 256; off <<= 1) {
            int v = (t >= off) ? sums[t - off] : 0;
            __syncthreads();
            sums[t] += v;
            __syncthreads();
        }
        int pos = (t > 0 ? sums[t - 1] : 0);
        #pragma unroll
        for (int i = 0; i < 8; ++i)
            if (mv[i]) cidx[b * Kn + pos++] = t * 8 + i;
        if (t == 255) {
            int total = sums[255];
            if (total == 0) { cidx[b * Kn] = 0; total = 1; }
            cnt[b] = total;
        }
    } else if (bid < 1032) {
        int e = (bid - 8) * 256 + t;
        float v = Wk[e] * 512.0f;
        f16 h = (f16)v;
        Wk_h[e] = h; Wk_l[e] = (f16)((v - (float)h) * 2048.0f);
        int r = e >> 9, c = e & 511;
        Wot[c * 512 + r] = bf16r(Wo[e]);
    } else {
        #pragma unroll
        for (int i = 0; i < 2; ++i) {
            int tt = t + i * 256;
            float s = 0.f;
            for (int n = 0; n < 512; n += 4) {
                f32x4 a = *(const f32x4*)(Wk + (size_t)tt * 512 + n);
                f32x4 q = *(const f32x4*)(bq + n);
                s += a[0]*q[0] + a[1]*q[1] + a[2]*q[2] + a[3]*q[3];
            }
            wvec[tt] = s * (1.0f / 512.0f);
            float s2 = 0.f;
            for (int h = 0; h < 512; ++h) s2 += bv[h] * Wo[h * 512 + tt];
            cvec[tt] = s2 + bo[tt];
        }
    }
}

// ---------------------------------------------------------------------------
// gemm_split<PREP>: fp16x2 3-product GEMM_BT, 64m x 128n tile, 48KB LDS dbuf.
//  PREP=1: Mt = A.Bt (=M x512), split out TRANSPOSED [n][m]
// ---------------------------------------------------------------------------
template<int PREP>
__global__ __launch_bounds__(256) void gemm_split(
    const float* __restrict__ Af,
    const f16* __restrict__ Bh_g, const f16* __restrict__ Bl_g,
    f16* __restrict__ Oh, f16* __restrict__ Ol)
{
    __shared__ __align__(16) f16 Ah[2][2048], Al[2][2048], Bh[2][4096], Bl[2][4096];
    const int tid = threadIdx.x, lane = tid & 63, wid = tid >> 6;
    const int l15 = lane & 15, lg = lane >> 4;
    const int m0 = blockIdx.x * 64, n0 = blockIdx.y * 128;
    const int srow = lane >> 2, sg = lane & 3;
    const int ar0 = tid >> 3, ac0 = (tid & 7) * 4;

    auto stageB = [&](int buf, int ks) {
        const int k0 = ks << 5;
        #pragma unroll
        for (int h = 0; h < 2; ++h) {
            int s = wid + h * 4;
            int row = s * 16 + srow;
            int goff = k0 + ((sg ^ swz(row)) << 3);
            gl_lds16(Bh_g + (size_t)(n0 + row) * Hn + goff, &Bh[buf][s * 512]);
            gl_lds16(Bl_g + (size_t)(n0 + row) * Hn + goff, &Bl[buf][s * 512]);
        }
    };
    auto writeA = [&](int buf, const f32x4* av) {
        #pragma unroll
        for (int rr = 0; rr < 2; ++rr) {
            int row = ar0 + rr * 32;
            f16x4 oh, ol;
            #pragma unroll
            for (int j = 0; j < 4; ++j) {
                f16 hh = (f16)av[rr][j];
                oh[j] = hh;
                ol[j] = (f16)((av[rr][j] - (float)hh) * 2048.0f);
            }
            int off = row * 32 + (((ac0 >> 3) ^ swz(row)) << 3) + (ac0 & 7);
            *(f16x4*)&Ah[buf][off] = oh;
            *(f16x4*)&Al[buf][off] = ol;
        }
    };

    const float* aSrc[2];
    #pragma unroll
    for (int rr = 0; rr < 2; ++rr)
        aSrc[rr] = Af + (size_t)(m0 + ar0 + rr * 32) * Hn;

    f32x4 a0[4][2] = {}, a1[4][2] = {};
    {
        f32x4 av[2];
        #pragma unroll
        for (int rr = 0; rr < 2; ++rr) av[rr] = *(const f32x4*)(aSrc[rr] + ac0);
        stageB(0, 0);
        writeA(0, av);
    }
    __syncthreads();
    #pragma unroll 1
    for (int ks = 0; ks < 16; ++ks) {
        const int cur = ks & 1, nxt = cur ^ 1;
        f32x4 av[2];
        if (ks < 15) {
            const int k1 = (ks + 1) << 5;
            #pragma unroll
            for (int rr = 0; rr < 2; ++rr) av[rr] = *(const f32x4*)(aSrc[rr] + k1 + ac0);
            stageB(nxt, ks + 1);
        }
        f16x8 fbh[2], fbl[2];
        #pragma unroll
        for (int fj = 0; fj < 2; ++fj) {
            int row = wid * 32 + fj * 16 + l15;
            int off = row * 32 + ((lg ^ swz(row)) << 3);
            fbh[fj] = *(f16x8*)&Bh[cur][off];
            fbl[fj] = *(f16x8*)&Bl[cur][off];
        }
        #pragma unroll
        for (int fi = 0; fi < 4; ++fi) {
            int row = fi * 16 + l15;
            int off = row * 32 + ((lg ^ swz(row)) << 3);
            f16x8 fah = *(f16x8*)&Ah[cur][off];
            f16x8 fal = *(f16x8*)&Al[cur][off];
            #pragma unroll
            for (int fj = 0; fj < 2; ++fj) {
                a0[fi][fj] = MFMA16(fah, fbh[fj], a0[fi][fj]);
                a1[fi][fj] = MFMA16(fah, fbl[fj], a1[fi][fj]);
                a1[fi][fj] = MFMA16(fal, fbh[fj], a1[fi][fj]);
            }
        }
        if (ks < 15) writeA(nxt, av);
        __syncthreads();
    }
    #pragma unroll
    for (int fi = 0; fi < 4; ++fi)
    #pragma unroll
    for (int fj = 0; fj < 2; ++fj)
    #pragma unroll
    for (int j = 0; j < 4; ++j) {
        int m = m0 + fi * 16 + lg * 4 + j;
        int n = n0 + wid * 32 + fj * 16 + l15;
        float v = a0[fi][fj][j] + a1[fi][fj][j] * (1.0f / 2048.0f);
        if (PREP == 0) v *= (1.0f / 512.0f);
        f16 h = (f16)v;
        f16 lo = (f16)((v - (float)h) * 2048.0f);
        size_t o = PREP ? ((size_t)n * Hn + m) : ((size_t)m * Hn + n);
        Oh[o] = h; Ol[o] = lo;
    }
}

// ---------------------------------------------------------------------------
// gemm_bfk0: NtB prep — A=Wv rows, out bf16 TRANSPOSED [n][m], no bias.
// ---------------------------------------------------------------------------
__global__ __launch_bounds__(256) void gemm_bfk0(
    const float* __restrict__ Af, const short* __restrict__ Bt,
    short* __restrict__ Out)
{
    __shared__ __align__(16) short As[2][2048], Bs[2][4096];
    const int tid = threadIdx.x, lane = tid & 63, wid = tid >> 6;
    const int l15 = lane & 15, lg = lane >> 4;
    const int m0 = blockIdx.x * 64, n0 = blockIdx.y * 128;
    const int srow = lane >> 2, sg = lane & 3;
    const int ar0 = tid >> 3, ac0 = (tid & 7) * 4;

    const float* aSrc[2];
    #pragma unroll
    for (int rr = 0; rr < 2; ++rr)
        aSrc[rr] = Af + (size_t)(m0 + ar0 + rr * 32) * Hn;

    auto stageB = [&](int buf, int ks) {
        const int k0 = ks << 5;
        #pragma unroll
        for (int h = 0; h < 2; ++h) {
            int s = wid + h * 4;
            int row = s * 16 + srow;
            int goff = k0 + ((sg ^ swz(row)) << 3);
            gl_lds16(Bt + (size_t)(n0 + row) * Hn + goff, &Bs[buf][s * 512]);
        }
    };
    auto writeA = [&](int buf, const f32x4* av) {
        #pragma unroll
        for (int rr = 0; rr < 2; ++rr) {
            int row = ar0 + rr * 32;
            s16x4 o;
            #pragma unroll
            for (int j = 0; j < 4; ++j) o[j] = bf16r(av[rr][j]);
            int off = row * 32 + (((ac0 >> 3) ^ swz(row)) << 3) + (ac0 & 7);
            *(s16x4*)&As[buf][off] = o;
        }
    };

    f32x4 acc[4][2] = {};
    {
        f32x4 av[2];
        #pragma unroll
        for (int rr = 0; rr < 2; ++rr) av[rr] = *(const f32x4*)(aSrc[rr] + ac0);
        stageB(0, 0);
        writeA(0, av);
    }
    __syncthreads();
    #pragma unroll 1
    for (int ks = 0; ks < 16; ++ks) {
        const int cur = ks & 1, nxt = cur ^ 1;
        f32x4 av[2];
        if (ks < 15) {
            const int k1 = (ks + 1) << 5;
            #pragma unroll
            for (int rr = 0; rr < 2; ++rr) av[rr] = *(const f32x4*)(aSrc[rr] + k1 + ac0);
            stageB(nxt, ks + 1);
        }
        s16x8 fb[2];
        #pragma unroll
        for (int fj = 0; fj < 2; ++fj) {
            int row = wid * 32 + fj * 16 + l15;
            fb[fj] = *(s16x8*)&Bs[cur][row * 32 + ((lg ^ swz(row)) << 3)];
        }
        #pragma unroll
        for (int fi = 0; fi < 4; ++fi) {
            int row = fi * 16 + l15;
            s16x8 fa = *(s16x8*)&As[cur][row * 32 + ((lg ^ swz(row)) << 3)];
            #pragma unroll
            for (int fj = 0; fj < 2; ++fj)
                acc[fi][fj] = MFMAB16(fa, fb[fj], acc[fi][fj]);
        }
        if (ks < 15) writeA(nxt, av);
        __syncthreads();
    }
    #pragma unroll
    for (int fi = 0; fi < 4; ++fi)
    #pragma unroll
    for (int fj = 0; fj < 2; ++fj)
    #pragma unroll
    for (int j = 0; j < 4; ++j) {
        int m = m0 + fi * 16 + lg * 4 + j;
        int n = n0 + wid * 32 + fj * 16 + l15;
        Out[(size_t)n * Hn + m] = bf16r(acc[fi][fj][j]);
    }
}

// ---------------------------------------------------------------------------
// qm_kconv: blocks 0..1023 = qM split GEMM (query.Mt, /512, split out);
// blocks 1024..5119 = kconv (raw-k gather -> f16 hi + beta).
// ---------------------------------------------------------------------------
__global__ __launch_bounds__(256) void qm_kconv(
    const float* __restrict__ query,
    const f16* __restrict__ Mt_h, const f16* __restrict__ Mt_l,
    f16* __restrict__ qM_h, f16* __restrict__ qM_l,
    const float* __restrict__ key_, const int* __restrict__ cidx,
    const int* __restrict__ cnt, const float* __restrict__ wvec,
    f16* __restrict__ Kc_h, float* __restrict__ beta)
{
    __shared__ __align__(16) f16 smem[2][2048 + 2048 + 4096 + 4096];
    const int bid = blockIdx.x;
    const int tid = threadIdx.x, lane = tid & 63, wid = tid >> 6;
    if (bid < 1024) {
        f16 (*Ah)[2048+2048+4096+4096] = smem;
        #define AH(b,i) Ah[b][i]
        #define AL(b,i) Ah[b][2048 + (i)]
        #define BH(b,i) Ah[b][4096 + (i)]
        #define BL(b,i) Ah[b][8192 + (i)]
        const int l15 = lane & 15, lg = lane >> 4;
        const int m0 = (bid & 255) * 64, n0 = (bid >> 8) * 128;
        const int srow = lane >> 2, sg = lane & 3;
        const int ar0 = tid >> 3, ac0 = (tid & 7) * 4;

        auto stageB = [&](int buf, int ks) {
            const int k0 = ks << 5;
            #pragma unroll
            for (int h = 0; h < 2; ++h) {
                int s = wid + h * 4;
                int row = s * 16 + srow;
                int goff = k0 + ((sg ^ swz(row)) << 3);
                gl_lds16(Mt_h + (size_t)(n0 + row) * Hn + goff, &BH(buf, s * 512));
                gl_lds16(Mt_l + (size_t)(n0 + row) * Hn + goff, &BL(buf, s * 512));
            }
        };
        auto writeA = [&](int buf, const f32x4* av) {
            #pragma unroll
            for (int rr = 0; rr < 2; ++rr) {
                int row = ar0 + rr * 32;
                f16x4 oh, ol;
                #pragma unroll
                for (int j = 0; j < 4; ++j) {
                    f16 hh = (f16)av[rr][j];
                    oh[j] = hh;
                    ol[j] = (f16)((av[rr][j] - (float)hh) * 2048.0f);
                }
                int off = row * 32 + (((ac0 >> 3) ^ swz(row)) << 3) + (ac0 & 7);
                *(f16x4*)&AH(buf, off) = oh;
                *(f16x4*)&AL(buf, off) = ol;
            }
        };

        const float* aSrc[2];
        #pragma unroll
        for (int rr = 0; rr < 2; ++rr)
            aSrc[rr] = query + (size_t)(m0 + ar0 + rr * 32) * Hn;

        f32x4 a0[4][2] = {}, a1[4][2] = {};
        {
            f32x4 av[2];
            #pragma unroll
            for (int rr = 0; rr < 2; ++rr) av[rr] = *(const f32x4*)(aSrc[rr] + ac0);
            stageB(0, 0);
            writeA(0, av);
        }
        __syncthreads();
        #pragma unroll 1
        for (int ks = 0; ks < 16; ++ks) {
            const int cur = ks & 1, nxt = cur ^ 1;
            f32x4 av[2];
            if (ks < 15) {
                const int k1 = (ks + 1) << 5;
                #pragma unroll
                for (int rr = 0; rr < 2; ++rr) av[rr] = *(const f32x4*)(aSrc[rr] + k1 + ac0);
                stageB(nxt, ks + 1);
            }
            f16x8 fbh[2], fbl[2];
            #pragma unroll
            for (int fj = 0; fj < 2; ++fj) {
                int row = wid * 32 + fj * 16 + l15;
                int off = row * 32 + ((lg ^ swz(row)) << 3);
                fbh[fj] = *(f16x8*)&BH(cur, off);
                fbl[fj] = *(f16x8*)&BL(cur, off);
            }
            #pragma unroll
            for (int fi = 0; fi < 4; ++fi) {
                int row = fi * 16 + l15;
                int off = row * 32 + ((lg ^ swz(row)) << 3);
                f16x8 fah = *(f16x8*)&AH(cur, off);
                f16x8 fal = *(f16x8*)&AL(cur, off);
                #pragma unroll
                for (int fj = 0; fj < 2; ++fj) {
                    a0[fi][fj] = MFMA16(fah, fbh[fj], a0[fi][fj]);
                    a1[fi][fj] = MFMA16(fah, fbl[fj], a1[fi][fj]);
                    a1[fi][fj] = MFMA16(fal, fbh[fj], a1[fi][fj]);
                }
            }
            if (ks < 15) writeA(nxt, av);
            __syncthreads();
        }
        #pragma unroll
        for (int fi = 0; fi < 4; ++fi)
        #pragma unroll
        for (int fj = 0; fj < 2; ++fj)
        #pragma unroll
        for (int j = 0; j < 4; ++j) {
            int m = m0 + fi * 16 + lg * 4 + j;
            int n = n0 + wid * 32 + fj * 16 + l15;
            float v = (a0[fi][fj][j] + a1[fi][fj][j] * (1.0f / 2048.0f)) * (1.0f / 512.0f);
            f16 h = (f16)v;
            qM_h[(size_t)m * Hn + n] = h;
            qM_l[(size_t)m * Hn + n] = (f16)((v - (float)h) * 2048.0f);
        }
        #undef AH
        #undef AL
        #undef BH
        #undef BL
    } else {
        int kb = bid - 1024;                 // [0, 4096)
        int b = kb >> 9;
        int j = (kb & 511) * 4 + wid;
        int cn = cnt[b];
        if (j >= cn) return;
        const float* src = key_ + (size_t)(b * Kn + cidx[b * Kn + j]) * Hn;
        size_t dst = (size_t)(b * Kn + j) * Hn;
        float s = 0.f;
        #pragma unroll
        for (int i = 0; i < 2; ++i) {
            int c0 = lane * 8 + i * 4;
            f32x4 v = *(const f32x4*)(src + c0);
            f32x4 w = *(const f32x4*)(wvec + c0);
            f16x4 oh;
            #pragma unroll
            for (int e = 0; e < 4; ++e) {
                oh[e] = (f16)v[e];
                s += v[e] * w[e];
            }
            *(f16x4*)(Kc_h + dst + c0) = oh;
        }
        #pragma unroll
        for (int sm = 1; sm < 64; sm <<= 1) s += __shfl_xor(s, sm, 64);
        if (lane == 0) beta[b * Kn + j] = s;
    }
}

// ---------------------------------------------------------------------------
// energy_approx: hi*hi single-product f16 GEMM, 64q x 128k tile, 4 waves
// (32-col strip each), 24KB LDS (~6 blocks/CU). NO energy matrix written —
// emits per-(row,128-chunk) top-2: (val1, compacted idx1, val2).
// ---------------------------------------------------------------------------
__global__ __launch_bounds__(256) void energy_approx(
    const f16* __restrict__ Qh, const f16* __restrict__ Kh,
    const float* __restrict__ beta, const int* __restrict__ cnt,
    float* __restrict__ pval1, int* __restrict__ pidx, float* __restrict__ pval2)
{
    __shared__ __align__(16) f16 Ah[2][2048], Bh[2][4096];
    const int tid = threadIdx.x, lane = tid & 63, wid = tid >> 6;
    const int l15 = lane & 15, lg = lane >> 4;
    const int qt = blockIdx.x, kc = blockIdx.y, b = blockIdx.z;
    const int cn = cnt[b];
    const int kbase = kc << 7;
    if (kbase >= cn) return;
    const int m0 = b * Qn + qt * 64;
    const int kr0 = b * Kn + kbase;
    const int srow = lane >> 2, sg = lane & 3;
    const float NEGINF = -__builtin_inff();

    auto stage = [&](int buf, int ks) {
        const int k0 = ks << 5;
        {
            int row = wid * 16 + srow;
            int goff = k0 + ((sg ^ swz(row)) << 3);
            gl_lds16(Qh + (size_t)(m0 + row) * Hn + goff, &Ah[buf][wid * 512]);
        }
        #pragma unroll
        for (int h = 0; h < 2; ++h) {
            int s = wid + h * 4;
            int row = s * 16 + srow;
            int goff = k0 + ((sg ^ swz(row)) << 3);
            gl_lds16(Kh + (size_t)(kr0 + row) * Hn + goff, &Bh[buf][s * 512]);
        }
    };

    f32x4 acc[4][2] = {};
    stage(0, 0);
    __syncthreads();
    #pragma unroll 1
    for (int ks = 0; ks < 16; ++ks) {
        const int cur = ks & 1;
        if (ks < 15) stage(cur ^ 1, ks + 1);
        f16x8 fb[2];
        #pragma unroll
        for (int fj = 0; fj < 2; ++fj) {
            int row = wid * 32 + fj * 16 + l15;
            fb[fj] = *(f16x8*)&Bh[cur][row * 32 + ((lg ^ swz(row)) << 3)];
        }
        #pragma unroll
        for (int fi = 0; fi < 4; ++fi) {
            int row = fi * 16 + l15;
            f16x8 fa = *(f16x8*)&Ah[cur][row * 32 + ((lg ^ swz(row)) << 3)];
            #pragma unroll
            for (int fj = 0; fj < 2; ++fj)
                acc[fi][fj] = MFMA16(fa, fb[fj], acc[fi][fj]);
        }
        __syncthreads();
    }
    // per-(row,chunk) top-2: reuse staging LDS as cross-wave scratch
    float (*bw1)[64] = (float(*)[64])&Ah[0][0];     // 1 KB
    int   (*bi1)[64] = (int(*)[64])&Ah[0][512];     // 1 KB
    float (*bw2)[64] = (float(*)[64])&Ah[1][0];     // 1 KB
    float bet[2]; int valid[2];
    #pragma unroll
    for (int fj = 0; fj < 2; ++fj) {
        int lc = wid * 32 + fj * 16 + l15;
        valid[fj] = (kbase + lc < cn);
        bet[fj] = valid[fj] ? beta[b * Kn + kbase + lc] : 0.0f;
    }
    #pragma unroll
    for (int fi = 0; fi < 4; ++fi)
    #pragma unroll
    for (int j = 0; j < 4; ++j) {
        int row = fi * 16 + lg * 4 + j;
        int lc0 = wid * 32 + l15, lc1 = lc0 + 16;
        float v0 = valid[0] ? (acc[fi][0][j] + bet[0]) : NEGINF;
        float v1 = valid[1] ? (acc[fi][1][j] + bet[1]) : NEGINF;
        float t1, t2; int ti;
        if (v1 > v0) { t1 = v1; ti = lc1; t2 = v0; }
        else         { t1 = v0; ti = lc0; t2 = v1; }
        #pragma unroll
        for (int sm = 1; sm < 16; sm <<= 1) {
            float o1 = __shfl_xor(t1, sm, 64);
            int   oi = __shfl_xor(ti, sm, 64);
            float o2 = __shfl_xor(t2, sm, 64);
            if (o1 > t1 || (o1 == t1 && oi < ti)) { t2 = fmaxf(t1, o2); t1 = o1; ti = oi; }
            else                                  { t2 = fmaxf(t2, o1); }
        }
        if (l15 == 0) { bw1[wid][row] = t1; bi1[wid][row] = ti; bw2[wid][row] = t2; }
    }
    __syncthreads();
    if (tid < 64) {
        float t1 = bw1[0][tid]; int ti = bi1[0][tid]; float t2 = bw2[0][tid];
        #pragma unroll
        for (int s = 1; s < 4; ++s) {
            float o1 = bw1[s][tid]; int oi = bi1[s][tid]; float o2 = bw2[s][tid];
            if (o1 > t1 || (o1 == t1 && oi < ti)) { t2 = fmaxf(t1, o2); t1 = o1; ti = oi; }
            else                                  { t2 = fmaxf(t2, o1); }
        }
        int m = m0 + tid;
        pval1[m * 16 + kc] = t1;
        pidx [m * 16 + kc] = kbase + ti;
        pval2[m * 16 + kc] = t2;
    }
}

// ---------------------------------------------------------------------------
// refine: one wave per q-row, chunk stats only. thr = gmax - 1.0 covers the
// approx error (2*eps <= 1.0). Fast path: single candidate, no chunk whose
// top-2 reaches thr. Slow path: exact f32 dots over a provable superset
// (chunk top-1s >= thr; full chunks whose top-2 >= thr). np tie-breaking.
// ---------------------------------------------------------------------------
__global__ __launch_bounds__(256) void refine(
    const float* __restrict__ pval1, const int* __restrict__ pidx,
    const float* __restrict__ pval2,
    const f16* __restrict__ qMh, const f16* __restrict__ qMl,
    const float* __restrict__ key_, const float* __restrict__ beta,
    const int* __restrict__ cidx, const int* __restrict__ cnt,
    int* __restrict__ idxArr)
{
    const int wid = threadIdx.x >> 6, lane = threadIdx.x & 63;
    const int m = blockIdx.x * 4 + wid;
    const int b = m >> 11;
    const int cn = cnt[b];
    const int nch = (cn + 127) >> 7;
    const float NEGINF = -__builtin_inff();

    float chv = (lane < nch) ? pval1[m * 16 + lane] : NEGINF;
    int   chi = (lane < nch) ? pidx [m * 16 + lane] : 0x7fffffff;
    float ch2 = (lane < nch) ? pval2[m * 16 + lane] : NEGINF;

    float gv = chv; int gi = chi;
    #pragma unroll
    for (int sm = 1; sm < 64; sm <<= 1) {
        float ov = __shfl_xor(gv, sm, 64);
        int   oi = __shfl_xor(gi, sm, 64);
        if (ov > gv || (ov == gv && oi < gi)) { gv = ov; gi = oi; }
    }
    const float thr = gv - 1.0f;
    unsigned long long candMask = __ballot(chv >= thr);
    unsigned long long scanMask = __ballot(ch2 >= thr);
    if (__popcll(candMask) == 1 && scanMask == 0ULL) {
        if (lane == 0) idxArr[m] = cidx[b * Kn + gi];
        return;
    }
    // exact path
    float q8[8];
    {
        f16x8 qh = *(const f16x8*)(qMh + (size_t)m * Hn + lane * 8);
        f16x8 ql = *(const f16x8*)(qMl + (size_t)m * Hn + lane * 8);
        #pragma unroll
        for (int e = 0; e < 8; ++e)
            q8[e] = (float)qh[e] + (float)ql[e] * (1.0f / 2048.0f);
    }
    float bestV = NEGINF; int bestOrig = 0x7fffffff;
    auto evalJ = [&](int j) {
        int orig = cidx[b * Kn + j];
        const float* kr = key_ + ((size_t)(b * Kn + orig)) * Hn + lane * 8;
        float d = 0.f;
        #pragma unroll
        for (int e = 0; e < 8; ++e) d += q8[e] * kr[e];
        #pragma unroll
        for (int sm = 1; sm < 64; sm <<= 1) d += __shfl_xor(d, sm, 64);
        d += beta[b * Kn + j];
        if (d > bestV || (d == bestV && orig < bestOrig)) { bestV = d; bestOrig = orig; }
    };
    for (int c = 0; c < nch; ++c) {
        float cv = __shfl(chv, c, 64);
        if (cv < thr) continue;
        float c2 = __shfl(ch2, c, 64);
        if (c2 >= thr) {
            int jend = min(128, cn - c * 128);
            for (int t = 0; t < jend; ++t) evalJ(c * 128 + t);
        } else {
            evalJ(__shfl(chi, c, 64));
        }
    }
    if (lane == 0) idxArr[m] = bestOrig;
}

// ---------------------------------------------------------------------------
// tail_fused: blocks 0..1023 = res GEMM (value[argmax].NtB + cvec, f32 out);
// blocks 1024.. = score one-hot rows (erases all scratch in score region).
// ---------------------------------------------------------------------------
__global__ __launch_bounds__(256) void tail_fused(
    const float* __restrict__ value, const short* __restrict__ NtB,
    const float* __restrict__ cvec, const int* __restrict__ idxArr,
    float* __restrict__ res, float* __restrict__ score)
{
    __shared__ __align__(16) short As[2][2048], Bs[2][4096];
    const int bid = blockIdx.x;
    const int tid = threadIdx.x, lane = tid & 63, wid = tid >> 6;
    if (bid >= 1024) {
        int m = bid - 1024;
        int c = idxArr[m];
        float* row = score + (size_t)m * Kn;
        #pragma unroll
        for (int i = 0; i < 2; ++i) {
            int v = tid + i * 256;
            f32x4 val = {0.f, 0.f, 0.f, 0.f};
            if ((c >> 2) == v) val[c & 3] = 1.0f;
            *(f32x4*)(row + v * 4) = val;
        }
        return;
    }
    const int l15 = lane & 15, lg = lane >> 4;
    const int m0 = (bid & 255) * 64, n0 = (bid >> 8) * 128;
    const int srow = lane >> 2, sg = lane & 3;
    const int ar0 = tid >> 3, ac0 = (tid & 7) * 4;

    const float* aSrc[2];
    #pragma unroll
    for (int rr = 0; rr < 2; ++rr) {
        int row = ar0 + rr * 32;
        int bb = m0 >> 11;
        aSrc[rr] = value + (size_t)(bb * Kn + idxArr[m0 + row]) * Hn;
    }

    auto stageB = [&](int buf, int ks) {
        const int k0 = ks << 5;
        #pragma unroll
        for (int h = 0; h < 2; ++h) {
            int s = wid + h * 4;
            int row = s * 16 + srow;
            int goff = k0 + ((sg ^ swz(row)) << 3);
            gl_lds16(NtB + (size_t)(n0 + row) * Hn + goff, &Bs[buf][s * 512]);
        }
    };
    auto writeA = [&](int buf, const f32x4* av) {
        #pragma unroll
        for (int rr = 0; rr < 2; ++rr) {
            int row = ar0 + rr * 32;
            s16x4 o;
            #pragma unroll
            for (int j = 0; j < 4; ++j) o[j] = bf16r(av[rr][j]);
            int off = row * 32 + (((ac0 >> 3) ^ swz(row)) << 3) + (ac0 & 7);
            *(s16x4*)&As[buf][off] = o;
        }
    };

    f32x4 acc[4][2] = {};
    {
        f32x4 av[2];
        #pragma unroll
        for (int rr = 0; rr < 2; ++rr) av[rr] = *(const f32x4*)(aSrc[rr] + ac0);
        stageB(0, 0);
        writeA(0, av);
    }
    __syncthreads();
    #pragma unroll 1
    for (int ks = 0; ks < 16; ++ks) {
        const int cur = ks & 1, nxt = cur ^ 1;
        f32x4 av[2];
        if (ks < 15) {
            const int k1 = (ks + 1) << 5;
            #pragma unroll
            for (int rr = 0; rr < 2; ++rr) av[rr] = *(const f32x4*)(aSrc[rr] + k1 + ac0);
            stageB(nxt, ks + 1);
        }
        s16x8 fb[2];
        #pragma unroll
        for (int fj = 0; fj < 2; ++fj) {
            int row = wid * 32 + fj * 16 + l15;
            fb[fj] = *(s16x8*)&Bs[cur][row * 32 + ((lg ^ swz(row)) << 3)];
        }
        #pragma unroll
        for (int fi = 0; fi < 4; ++fi) {
            int row = fi * 16 + l15;
            s16x8 fa = *(s16x8*)&As[cur][row * 32 + ((lg ^ swz(row)) << 3)];
            #pragma unroll
            for (int fj = 0; fj < 2; ++fj)
                acc[fi][fj] = MFMAB16(fa, fb[fj], acc[fi][fj]);
        }
        if (ks < 15) writeA(nxt, av);
        __syncthreads();
    }
    #pragma unroll
    for (int fi = 0; fi < 4; ++fi)
    #pragma unroll
    for (int fj = 0; fj < 2; ++fj)
    #pragma unroll
    for (int j = 0; j < 4; ++j) {
        int m = m0 + fi * 16 + lg * 4 + j;
        int n = n0 + wid * 32 + fj * 16 + l15;
        res[(size_t)m * Hn + n] = acc[fi][fj][j] + cvec[n];
    }
}

// ---------------------------------------------------------------------------
extern "C" void kernel_launch(void* const* d_in, const int* in_sizes, int n_in,
                              void* d_out, int out_size, void* d_ws, size_t ws_size,
                              hipStream_t stream)
{
    const float* query = (const float*)d_in[0];
    const float* key_  = (const float*)d_in[1];
    const float* value = (const float*)d_in[2];
    const int*   mask  = (const int*)d_in[3];
    const float* Wq = (const float*)d_in[4];
    const float* bq = (const float*)d_in[5];
    const float* Wk = (const float*)d_in[6];
    const float* bv = (const float*)d_in[9];
    const float* Wv = (const float*)d_in[8];
    const float* Wo = (const float*)d_in[10];
    const float* bo = (const float*)d_in[11];

    float* res = (float*)d_out;                       // (B,Q,H) f32
    float* scoreBase = res + (size_t)Mn * Hn;         // (B,Q,K) f32, 128 MiB
    char* sc = (char*)scoreBase;                      // scratch inside score region
    constexpr size_t MB = 1u << 20;
    f16*   qM_h = (f16*)(sc + 0 * MB);                // 16 MB
    f16*   qM_l = (f16*)(sc + 16 * MB);               // 16 MB
    f16*   Kc_h = (f16*)(sc + 32 * MB);               // 16 MB
    char*  wb   = sc + 112 * MB;
    f16*   Mt_h = (f16*)(wb);
    f16*   Mt_l = (f16*)(wb + 524288);
    f16*   Wk_h = (f16*)(wb + 2 * 524288);
    f16*   Wk_l = (f16*)(wb + 3 * 524288);
    short* Wot  = (short*)(wb + 4 * 524288);
    float* wvec = (float*)(wb + 5 * 524288);
    float* beta = (float*)(wb + 5 * 524288 + 8192);              // 64 KB
    int*   cidx = (int*)(wb + 5 * 524288 + 8192 + 65536);        // 64 KB
    float* pval1 = (float*)(wb + 6 * 524288);                    // 1 MB
    int*   pidx  = (int*)(wb + 8 * 524288);                      // 1 MB
    float* pval2 = (float*)(wb + 10 * 524288);                   // 1 MB

    int*   idxArr = (int*)d_ws;                                  // 64 KB
    int*   cnt    = (int*)d_ws + 16384;                          // 32 B
    float* cvec   = (float*)((char*)d_ws + 65600);               // 2 KB
    short* NtB    = (short*)((char*)d_ws + 67648);               // 512 KB

    prep_all<<<1033, 256, 0, stream>>>(mask, Wk, Wo, bq, bv, bo,
                                       cidx, cnt, Wk_h, Wk_l, Wot, wvec, cvec);

    gemm_split<1><<<dim3(8, 4), 256, 0, stream>>>(Wq, Wk_h, Wk_l, Mt_h, Mt_l);
    gemm_bfk0<<<dim3(8, 4), 256, 0, stream>>>(Wv, Wot, NtB);

    qm_kconv<<<5120, 256, 0, stream>>>(query, Mt_h, Mt_l, qM_h, qM_l,
                                       key_, cidx, cnt, wvec, Kc_h, beta);

    energy_approx<<<dim3(Qn / 64, 16, Bn), 256, 0, stream>>>(
        qM_h, Kc_h, beta, cnt, pval1, pidx, pval2);

    refine<<<Mn / 4, 256, 0, stream>>>(
        pval1, pidx, pval2, qM_h, qM_l, key_, beta, cidx, cnt, idxArr);

    tail_fused<<<1024 + Mn, 256, 0, stream>>>(value, NtB, cvec, idxArr,
                                              res, scoreBase);
}

// Round 12
// 296.820 us; speedup vs baseline: 1.3104x; 1.3104x over previous
//
#include <hip/hip_runtime.h>

typedef _Float16 f16;
typedef f16 f16x8 __attribute__((ext_vector_type(8)));
typedef f16 f16x4 __attribute__((ext_vector_type(4)));
typedef short s16x8 __attribute__((ext_vector_type(8)));
typedef short s16x4 __attribute__((ext_vector_type(4)));
typedef float f32x4 __attribute__((ext_vector_type(4)));

#define MFMA16(a,b,c)  __builtin_amdgcn_mfma_f32_16x16x32_f16(a,b,c,0,0,0)
#define MFMAB16(a,b,c) __builtin_amdgcn_mfma_f32_16x16x32_bf16(a,b,c,0,0,0)

static constexpr int Bn = 8, Qn = 2048, Kn = 2048, Hn = 512;
static constexpr int Mn = Bn * Qn;           // 16384 flat rows

typedef __attribute__((address_space(1))) const unsigned int as1_uint;
typedef __attribute__((address_space(3))) unsigned int as3_uint;

__device__ __forceinline__ void gl_lds16(const void* g, void* l) {
    __builtin_amdgcn_global_load_lds((as1_uint*)g, (as3_uint*)l, 16, 0, 0);
}

__device__ __forceinline__ short bf16r(float x) {
    unsigned u = __builtin_bit_cast(unsigned, x);
    u += 0x7fffu + ((u >> 16) & 1u);
    return (short)(u >> 16);
}

// swizzle granule: 2-way (free) bank aliasing for ds_read_b128 column reads
__device__ __forceinline__ int swz(int row) { return (row >> 1) & 3; }

// ---------------------------------------------------------------------------
// prep_all: blocks 0..7 compact_mask; 8..1031 weight split/transpose;
// 1032 bias vectors.
// ---------------------------------------------------------------------------
__global__ __launch_bounds__(256) void prep_all(
    const int* __restrict__ mask, const float* __restrict__ Wk,
    const float* __restrict__ Wo, const float* __restrict__ bq,
    const float* __restrict__ bv, const float* __restrict__ bo,
    int* __restrict__ cidx, int* __restrict__ cnt,
    f16* __restrict__ Wk_h, f16* __restrict__ Wk_l, short* __restrict__ Wot,
    float* __restrict__ wvec, float* __restrict__ cvec)
{
    const int bid = blockIdx.x, t = threadIdx.x;
    if (bid < 8) {
        __shared__ int sums[256];
        int b = bid;
        int base = b * Kn + t * 8;
        int mv[8]; int s = 0;
        #pragma unroll
        for (int i = 0; i < 8; ++i) { mv[i] = (mask[base + i] == 0); s += mv[i]; }
        sums[t] = s;
        __syncthreads();
        for (int off = 1; off < 256; off <<= 1) {
            int v = (t >= off) ? sums[t - off] : 0;
            __syncthreads();
            sums[t] += v;
            __syncthreads();
        }
        int pos = (t > 0 ? sums[t - 1] : 0);
        #pragma unroll
        for (int i = 0; i < 8; ++i)
            if (mv[i]) cidx[b * Kn + pos++] = t * 8 + i;
        if (t == 255) {
            int total = sums[255];
            if (total == 0) { cidx[b * Kn] = 0; total = 1; }
            cnt[b] = total;
        }
    } else if (bid < 1032) {
        int e = (bid - 8) * 256 + t;
        float v = Wk[e] * 512.0f;
        f16 h = (f16)v;
        Wk_h[e] = h; Wk_l[e] = (f16)((v - (float)h) * 2048.0f);
        int r = e >> 9, c = e & 511;
        Wot[c * 512 + r] = bf16r(Wo[e]);
    } else {
        #pragma unroll
        for (int i = 0; i < 2; ++i) {
            int tt = t + i * 256;
            float s = 0.f;
            for (int n = 0; n < 512; n += 4) {
                f32x4 a = *(const f32x4*)(Wk + (size_t)tt * 512 + n);
                f32x4 q = *(const f32x4*)(bq + n);
                s += a[0]*q[0] + a[1]*q[1] + a[2]*q[2] + a[3]*q[3];
            }
            wvec[tt] = s * (1.0f / 512.0f);
            float s2 = 0.f;
            for (int h = 0; h < 512; ++h) s2 += bv[h] * Wo[h * 512 + tt];
            cvec[tt] = s2 + bo[tt];
        }
    }
}

// ---------------------------------------------------------------------------
// gemm_split<PREP>: fp16x2 3-product GEMM_BT, 64m x 128n tile, 48KB LDS dbuf.
//  PREP=1: Mt = A.Bt (=M x512), split out TRANSPOSED [n][m]
// ---------------------------------------------------------------------------
template<int PREP>
__global__ __launch_bounds__(256) void gemm_split(
    const float* __restrict__ Af,
    const f16* __restrict__ Bh_g, const f16* __restrict__ Bl_g,
    f16* __restrict__ Oh, f16* __restrict__ Ol)
{
    __shared__ __align__(16) f16 Ah[2][2048], Al[2][2048], Bh[2][4096], Bl[2][4096];
    const int tid = threadIdx.x, lane = tid & 63, wid = tid >> 6;
    const int l15 = lane & 15, lg = lane >> 4;
    const int m0 = blockIdx.x * 64, n0 = blockIdx.y * 128;
    const int srow = lane >> 2, sg = lane & 3;
    const int ar0 = tid >> 3, ac0 = (tid & 7) * 4;

    auto stageB = [&](int buf, int ks) {
        const int k0 = ks << 5;
        #pragma unroll
        for (int h = 0; h < 2; ++h) {
            int s = wid + h * 4;
            int row = s * 16 + srow;
            int goff = k0 + ((sg ^ swz(row)) << 3);
            gl_lds16(Bh_g + (size_t)(n0 + row) * Hn + goff, &Bh[buf][s * 512]);
            gl_lds16(Bl_g + (size_t)(n0 + row) * Hn + goff, &Bl[buf][s * 512]);
        }
    };
    auto writeA = [&](int buf, const f32x4* av) {
        #pragma unroll
        for (int rr = 0; rr < 2; ++rr) {
            int row = ar0 + rr * 32;
            f16x4 oh, ol;
            #pragma unroll
            for (int j = 0; j < 4; ++j) {
                f16 hh = (f16)av[rr][j];
                oh[j] = hh;
                ol[j] = (f16)((av[rr][j] - (float)hh) * 2048.0f);
            }
            int off = row * 32 + (((ac0 >> 3) ^ swz(row)) << 3) + (ac0 & 7);
            *(f16x4*)&Ah[buf][off] = oh;
            *(f16x4*)&Al[buf][off] = ol;
        }
    };

    const float* aSrc[2];
    #pragma unroll
    for (int rr = 0; rr < 2; ++rr)
        aSrc[rr] = Af + (size_t)(m0 + ar0 + rr * 32) * Hn;

    f32x4 a0[4][2] = {}, a1[4][2] = {};
    {
        f32x4 av[2];
        #pragma unroll
        for (int rr = 0; rr < 2; ++rr) av[rr] = *(const f32x4*)(aSrc[rr] + ac0);
        stageB(0, 0);
        writeA(0, av);
    }
    __syncthreads();
    #pragma unroll 1
    for (int ks = 0; ks < 16; ++ks) {
        const int cur = ks & 1, nxt = cur ^ 1;
        f32x4 av[2];
        if (ks < 15) {
            const int k1 = (ks + 1) << 5;
            #pragma unroll
            for (int rr = 0; rr < 2; ++rr) av[rr] = *(const f32x4*)(aSrc[rr] + k1 + ac0);
            stageB(nxt, ks + 1);
        }
        f16x8 fbh[2], fbl[2];
        #pragma unroll
        for (int fj = 0; fj < 2; ++fj) {
            int row = wid * 32 + fj * 16 + l15;
            int off = row * 32 + ((lg ^ swz(row)) << 3);
            fbh[fj] = *(f16x8*)&Bh[cur][off];
            fbl[fj] = *(f16x8*)&Bl[cur][off];
        }
        #pragma unroll
        for (int fi = 0; fi < 4; ++fi) {
            int row = fi * 16 + l15;
            int off = row * 32 + ((lg ^ swz(row)) << 3);
            f16x8 fah = *(f16x8*)&Ah[cur][off];
            f16x8 fal = *(f16x8*)&Al[cur][off];
            #pragma unroll
            for (int fj = 0; fj < 2; ++fj) {
                a0[fi][fj] = MFMA16(fah, fbh[fj], a0[fi][fj]);
                a1[fi][fj] = MFMA16(fah, fbl[fj], a1[fi][fj]);
                a1[fi][fj] = MFMA16(fal, fbh[fj], a1[fi][fj]);
            }
        }
        if (ks < 15) writeA(nxt, av);
        __syncthreads();
    }
    #pragma unroll
    for (int fi = 0; fi < 4; ++fi)
    #pragma unroll
    for (int fj = 0; fj < 2; ++fj)
    #pragma unroll
    for (int j = 0; j < 4; ++j) {
        int m = m0 + fi * 16 + lg * 4 + j;
        int n = n0 + wid * 32 + fj * 16 + l15;
        float v = a0[fi][fj][j] + a1[fi][fj][j] * (1.0f / 2048.0f);
        if (PREP == 0) v *= (1.0f / 512.0f);
        f16 h = (f16)v;
        f16 lo = (f16)((v - (float)h) * 2048.0f);
        size_t o = PREP ? ((size_t)n * Hn + m) : ((size_t)m * Hn + n);
        Oh[o] = h; Ol[o] = lo;
    }
}

// ---------------------------------------------------------------------------
// gemm_bfk0: NtB prep — A=Wv rows, out bf16 TRANSPOSED [n][m], no bias.
// ---------------------------------------------------------------------------
__global__ __launch_bounds__(256) void gemm_bfk0(
    const float* __restrict__ Af, const short* __restrict__ Bt,
    short* __restrict__ Out)
{
    __shared__ __align__(16) short As[2][2048], Bs[2][4096];
    const int tid = threadIdx.x, lane = tid & 63, wid = tid >> 6;
    const int l15 = lane & 15, lg = lane >> 4;
    const int m0 = blockIdx.x * 64, n0 = blockIdx.y * 128;
    const int srow = lane >> 2, sg = lane & 3;
    const int ar0 = tid >> 3, ac0 = (tid & 7) * 4;

    const float* aSrc[2];
    #pragma unroll
    for (int rr = 0; rr < 2; ++rr)
        aSrc[rr] = Af + (size_t)(m0 + ar0 + rr * 32) * Hn;

    auto stageB = [&](int buf, int ks) {
        const int k0 = ks << 5;
        #pragma unroll
        for (int h = 0; h < 2; ++h) {
            int s = wid + h * 4;
            int row = s * 16 + srow;
            int goff = k0 + ((sg ^ swz(row)) << 3);
            gl_lds16(Bt + (size_t)(n0 + row) * Hn + goff, &Bs[buf][s * 512]);
        }
    };
    auto writeA = [&](int buf, const f32x4* av) {
        #pragma unroll
        for (int rr = 0; rr < 2; ++rr) {
            int row = ar0 + rr * 32;
            s16x4 o;
            #pragma unroll
            for (int j = 0; j < 4; ++j) o[j] = bf16r(av[rr][j]);
            int off = row * 32 + (((ac0 >> 3) ^ swz(row)) << 3) + (ac0 & 7);
            *(s16x4*)&As[buf][off] = o;
        }
    };

    f32x4 acc[4][2] = {};
    {
        f32x4 av[2];
        #pragma unroll
        for (int rr = 0; rr < 2; ++rr) av[rr] = *(const f32x4*)(aSrc[rr] + ac0);
        stageB(0, 0);
        writeA(0, av);
    }
    __syncthreads();
    #pragma unroll 1
    for (int ks = 0; ks < 16; ++ks) {
        const int cur = ks & 1, nxt = cur ^ 1;
        f32x4 av[2];
        if (ks < 15) {
            const int k1 = (ks + 1) << 5;
            #pragma unroll
            for (int rr = 0; rr < 2; ++rr) av[rr] = *(const f32x4*)(aSrc[rr] + k1 + ac0);
            stageB(nxt, ks + 1);
        }
        s16x8 fb[2];
        #pragma unroll
        for (int fj = 0; fj < 2; ++fj) {
            int row = wid * 32 + fj * 16 + l15;
            fb[fj] = *(s16x8*)&Bs[cur][row * 32 + ((lg ^ swz(row)) << 3)];
        }
        #pragma unroll
        for (int fi = 0; fi < 4; ++fi) {
            int row = fi * 16 + l15;
            s16x8 fa = *(s16x8*)&As[cur][row * 32 + ((lg ^ swz(row)) << 3)];
            #pragma unroll
            for (int fj = 0; fj < 2; ++fj)
                acc[fi][fj] = MFMAB16(fa, fb[fj], acc[fi][fj]);
        }
        if (ks < 15) writeA(nxt, av);
        __syncthreads();
    }
    #pragma unroll
    for (int fi = 0; fi < 4; ++fi)
    #pragma unroll
    for (int fj = 0; fj < 2; ++fj)
    #pragma unroll
    for (int j = 0; j < 4; ++j) {
        int m = m0 + fi * 16 + lg * 4 + j;
        int n = n0 + wid * 32 + fj * 16 + l15;
        Out[(size_t)n * Hn + m] = bf16r(acc[fi][fj][j]);
    }
}

// ---------------------------------------------------------------------------
// qm_kconv: blocks 0..1023 = qM split GEMM (query.Mt, /512, split out);
// blocks 1024..5119 = kconv (raw-k gather -> f16 hi + beta).
// ---------------------------------------------------------------------------
__global__ __launch_bounds__(256) void qm_kconv(
    const float* __restrict__ query,
    const f16* __restrict__ Mt_h, const f16* __restrict__ Mt_l,
    f16* __restrict__ qM_h, f16* __restrict__ qM_l,
    const float* __restrict__ key_, const int* __restrict__ cidx,
    const int* __restrict__ cnt, const float* __restrict__ wvec,
    f16* __restrict__ Kc_h, float* __restrict__ beta)
{
    __shared__ __align__(16) f16 smem[2][2048 + 2048 + 4096 + 4096];
    const int bid = blockIdx.x;
    const int tid = threadIdx.x, lane = tid & 63, wid = tid >> 6;
    if (bid < 1024) {
        f16 (*Ah)[2048+2048+4096+4096] = smem;
        #define AH(b,i) Ah[b][i]
        #define AL(b,i) Ah[b][2048 + (i)]
        #define BH(b,i) Ah[b][4096 + (i)]
        #define BL(b,i) Ah[b][8192 + (i)]
        const int l15 = lane & 15, lg = lane >> 4;
        const int m0 = (bid & 255) * 64, n0 = (bid >> 8) * 128;
        const int srow = lane >> 2, sg = lane & 3;
        const int ar0 = tid >> 3, ac0 = (tid & 7) * 4;

        auto stageB = [&](int buf, int ks) {
            const int k0 = ks << 5;
            #pragma unroll
            for (int h = 0; h < 2; ++h) {
                int s = wid + h * 4;
                int row = s * 16 + srow;
                int goff = k0 + ((sg ^ swz(row)) << 3);
                gl_lds16(Mt_h + (size_t)(n0 + row) * Hn + goff, &BH(buf, s * 512));
                gl_lds16(Mt_l + (size_t)(n0 + row) * Hn + goff, &BL(buf, s * 512));
            }
        };
        auto writeA = [&](int buf, const f32x4* av) {
            #pragma unroll
            for (int rr = 0; rr < 2; ++rr) {
                int row = ar0 + rr * 32;
                f16x4 oh, ol;
                #pragma unroll
                for (int j = 0; j < 4; ++j) {
                    f16 hh = (f16)av[rr][j];
                    oh[j] = hh;
                    ol[j] = (f16)((av[rr][j] - (float)hh) * 2048.0f);
                }
                int off = row * 32 + (((ac0 >> 3) ^ swz(row)) << 3) + (ac0 & 7);
                *(f16x4*)&AH(buf, off) = oh;
                *(f16x4*)&AL(buf, off) = ol;
            }
        };

        const float* aSrc[2];
        #pragma unroll
        for (int rr = 0; rr < 2; ++rr)
            aSrc[rr] = query + (size_t)(m0 + ar0 + rr * 32) * Hn;

        f32x4 a0[4][2] = {}, a1[4][2] = {};
        {
            f32x4 av[2];
            #pragma unroll
            for (int rr = 0; rr < 2; ++rr) av[rr] = *(const f32x4*)(aSrc[rr] + ac0);
            stageB(0, 0);
            writeA(0, av);
        }
        __syncthreads();
        #pragma unroll 1
        for (int ks = 0; ks < 16; ++ks) {
            const int cur = ks & 1, nxt = cur ^ 1;
            f32x4 av[2];
            if (ks < 15) {
                const int k1 = (ks + 1) << 5;
                #pragma unroll
                for (int rr = 0; rr < 2; ++rr) av[rr] = *(const f32x4*)(aSrc[rr] + k1 + ac0);
                stageB(nxt, ks + 1);
            }
            f16x8 fbh[2], fbl[2];
            #pragma unroll
            for (int fj = 0; fj < 2; ++fj) {
                int row = wid * 32 + fj * 16 + l15;
                int off = row * 32 + ((lg ^ swz(row)) << 3);
                fbh[fj] = *(f16x8*)&BH(cur, off);
                fbl[fj] = *(f16x8*)&BL(cur, off);
            }
            #pragma unroll
            for (int fi = 0; fi < 4; ++fi) {
                int row = fi * 16 + l15;
                int off = row * 32 + ((lg ^ swz(row)) << 3);
                f16x8 fah = *(f16x8*)&AH(cur, off);
                f16x8 fal = *(f16x8*)&AL(cur, off);
                #pragma unroll
                for (int fj = 0; fj < 2; ++fj) {
                    a0[fi][fj] = MFMA16(fah, fbh[fj], a0[fi][fj]);
                    a1[fi][fj] = MFMA16(fah, fbl[fj], a1[fi][fj]);
                    a1[fi][fj] = MFMA16(fal, fbh[fj], a1[fi][fj]);
                }
            }
            if (ks < 15) writeA(nxt, av);
            __syncthreads();
        }
        #pragma unroll
        for (int fi = 0; fi < 4; ++fi)
        #pragma unroll
        for (int fj = 0; fj < 2; ++fj)
        #pragma unroll
        for (int j = 0; j < 4; ++j) {
            int m = m0 + fi * 16 + lg * 4 + j;
            int n = n0 + wid * 32 + fj * 16 + l15;
            float v = (a0[fi][fj][j] + a1[fi][fj][j] * (1.0f / 2048.0f)) * (1.0f / 512.0f);
            f16 h = (f16)v;
            qM_h[(size_t)m * Hn + n] = h;
            qM_l[(size_t)m * Hn + n] = (f16)((v - (float)h) * 2048.0f);
        }
        #undef AH
        #undef AL
        #undef BH
        #undef BL
    } else {
        int kb = bid - 1024;                 // [0, 4096)
        int b = kb >> 9;
        int j = (kb & 511) * 4 + wid;
        int cn = cnt[b];
        if (j >= cn) return;
        const float* src = key_ + (size_t)(b * Kn + cidx[b * Kn + j]) * Hn;
        size_t dst = (size_t)(b * Kn + j) * Hn;
        float s = 0.f;
        #pragma unroll
        for (int i = 0; i < 2; ++i) {
            int c0 = lane * 8 + i * 4;
            f32x4 v = *(const f32x4*)(src + c0);
            f32x4 w = *(const f32x4*)(wvec + c0);
            f16x4 oh;
            #pragma unroll
            for (int e = 0; e < 4; ++e) {
                oh[e] = (f16)v[e];
                s += v[e] * w[e];
            }
            *(f16x4*)(Kc_h + dst + c0) = oh;
        }
        #pragma unroll
        for (int sm = 1; sm < 64; sm <<= 1) s += __shfl_xor(s, sm, 64);
        if (lane == 0) beta[b * Kn + j] = s;
    }
}

// ---------------------------------------------------------------------------
// energy_approx: hi*hi single-product f16 GEMM, 64q x 128k tile, 4 waves
// (32-col strip each), 24KB LDS (~6 blocks/CU). NO energy matrix written —
// emits per-(row,128-chunk) top-2: (val1, compacted idx1, val2).
// ---------------------------------------------------------------------------
__global__ __launch_bounds__(256) void energy_approx(
    const f16* __restrict__ Qh, const f16* __restrict__ Kh,
    const float* __restrict__ beta, const int* __restrict__ cnt,
    float* __restrict__ pval1, int* __restrict__ pidx, float* __restrict__ pval2)
{
    __shared__ __align__(16) f16 Ah[2][2048], Bh[2][4096];
    const int tid = threadIdx.x, lane = tid & 63, wid = tid >> 6;
    const int l15 = lane & 15, lg = lane >> 4;
    const int qt = blockIdx.x, kc = blockIdx.y, b = blockIdx.z;
    const int cn = cnt[b];
    const int kbase = kc << 7;
    if (kbase >= cn) return;
    const int m0 = b * Qn + qt * 64;
    const int kr0 = b * Kn + kbase;
    const int srow = lane >> 2, sg = lane & 3;
    const float NEGINF = -__builtin_inff();

    auto stage = [&](int buf, int ks) {
        const int k0 = ks << 5;
        {
            int row = wid * 16 + srow;
            int goff = k0 + ((sg ^ swz(row)) << 3);
            gl_lds16(Qh + (size_t)(m0 + row) * Hn + goff, &Ah[buf][wid * 512]);
        }
        #pragma unroll
        for (int h = 0; h < 2; ++h) {
            int s = wid + h * 4;
            int row = s * 16 + srow;
            int goff = k0 + ((sg ^ swz(row)) << 3);
            gl_lds16(Kh + (size_t)(kr0 + row) * Hn + goff, &Bh[buf][s * 512]);
        }
    };

    f32x4 acc[4][2] = {};
    stage(0, 0);
    __syncthreads();
    #pragma unroll 1
    for (int ks = 0; ks < 16; ++ks) {
        const int cur = ks & 1;
        if (ks < 15) stage(cur ^ 1, ks + 1);
        f16x8 fb[2];
        #pragma unroll
        for (int fj = 0; fj < 2; ++fj) {
            int row = wid * 32 + fj * 16 + l15;
            fb[fj] = *(f16x8*)&Bh[cur][row * 32 + ((lg ^ swz(row)) << 3)];
        }
        #pragma unroll
        for (int fi = 0; fi < 4; ++fi) {
            int row = fi * 16 + l15;
            f16x8 fa = *(f16x8*)&Ah[cur][row * 32 + ((lg ^ swz(row)) << 3)];
            #pragma unroll
            for (int fj = 0; fj < 2; ++fj)
                acc[fi][fj] = MFMA16(fa, fb[fj], acc[fi][fj]);
        }
        __syncthreads();
    }
    // per-(row,chunk) top-2: reuse staging LDS as cross-wave scratch
    float (*bw1)[64] = (float(*)[64])&Ah[0][0];     // 1 KB
    int   (*bi1)[64] = (int(*)[64])&Ah[0][512];     // 1 KB
    float (*bw2)[64] = (float(*)[64])&Ah[1][0];     // 1 KB
    float bet[2]; int valid[2];
    #pragma unroll
    for (int fj = 0; fj < 2; ++fj) {
        int lc = wid * 32 + fj * 16 + l15;
        valid[fj] = (kbase + lc < cn);
        bet[fj] = valid[fj] ? beta[b * Kn + kbase + lc] : 0.0f;
    }
    #pragma unroll
    for (int fi = 0; fi < 4; ++fi)
    #pragma unroll
    for (int j = 0; j < 4; ++j) {
        int row = fi * 16 + lg * 4 + j;
        int lc0 = wid * 32 + l15, lc1 = lc0 + 16;
        float v0 = valid[0] ? (acc[fi][0][j] + bet[0]) : NEGINF;
        float v1 = valid[1] ? (acc[fi][1][j] + bet[1]) : NEGINF;
        float t1, t2; int ti;
        if (v1 > v0) { t1 = v1; ti = lc1; t2 = v0; }
        else         { t1 = v0; ti = lc0; t2 = v1; }
        #pragma unroll
        for (int sm = 1; sm < 16; sm <<= 1) {
            float o1 = __shfl_xor(t1, sm, 64);
            int   oi = __shfl_xor(ti, sm, 64);
            float o2 = __shfl_xor(t2, sm, 64);
            if (o1 > t1 || (o1 == t1 && oi < ti)) { t2 = fmaxf(t1, o2); t1 = o1; ti = oi; }
            else                                  { t2 = fmaxf(t2, o1); }
        }
        if (l15 == 0) { bw1[wid][row] = t1; bi1[wid][row] = ti; bw2[wid][row] = t2; }
    }
    __syncthreads();
    if (tid < 64) {
        float t1 = bw1[0][tid]; int ti = bi1[0][tid]; float t2 = bw2[0][tid];
        #pragma unroll
        for (int s = 1; s < 4; ++s) {
            float o1 = bw1[s][tid]; int oi = bi1[s][tid]; float o2 = bw2[s][tid];
            if (o1 > t1 || (o1 == t1 && oi < ti)) { t2 = fmaxf(t1, o2); t1 = o1; ti = oi; }
            else                                  { t2 = fmaxf(t2, o1); }
        }
        int m = m0 + tid;
        pval1[m * 16 + kc] = t1;
        pidx [m * 16 + kc] = kbase + ti;
        pval2[m * 16 + kc] = t2;
    }
}

// ---------------------------------------------------------------------------
// refine v3: one wave per q-row, chunk stats only, window 0.35 (>=3.7x the
// measured-max approx error). Fast path: single candidate. Slow path:
// LANE-PARALLEL exact f32 dots — each lane owns one candidate and streams a
// serial 512-dot (q row broadcast via L1, k row per-lane); single wave
// reduce with np tie-break at the end.
// ---------------------------------------------------------------------------
__global__ __launch_bounds__(256) void refine(
    const float* __restrict__ pval1, const int* __restrict__ pidx,
    const float* __restrict__ pval2,
    const f16* __restrict__ qMh, const f16* __restrict__ qMl,
    const float* __restrict__ key_, const float* __restrict__ beta,
    const int* __restrict__ cidx, const int* __restrict__ cnt,
    int* __restrict__ idxArr)
{
    const int wid = threadIdx.x >> 6, lane = threadIdx.x & 63;
    const int m = blockIdx.x * 4 + wid;
    const int b = m >> 11;
    const int cn = cnt[b];
    const int nch = (cn + 127) >> 7;
    const float NEGINF = -__builtin_inff();

    float chv = (lane < nch) ? pval1[m * 16 + lane] : NEGINF;
    int   chi = (lane < nch) ? pidx [m * 16 + lane] : 0x7fffffff;
    float ch2 = (lane < nch) ? pval2[m * 16 + lane] : NEGINF;

    float gv = chv; int gi = chi;
    #pragma unroll
    for (int sm = 1; sm < 64; sm <<= 1) {
        float ov = __shfl_xor(gv, sm, 64);
        int   oi = __shfl_xor(gi, sm, 64);
        if (ov > gv || (ov == gv && oi < gi)) { gv = ov; gi = oi; }
    }
    const float thr = gv - 0.35f;
    unsigned long long candMask = __ballot(chv >= thr);
    unsigned long long scanMask = __ballot(ch2 >= thr);
    if (__popcll(candMask) == 1 && scanMask == 0ULL) {
        if (lane == 0) idxArr[m] = cidx[b * Kn + gi];
        return;
    }
    // slow path: lane-parallel exact evaluation
    const f16* qhRow = qMh + (size_t)m * Hn;
    const f16* qlRow = qMl + (size_t)m * Hn;
    float bestV = NEGINF; int bestOrig = 0x7fffffff;

    auto evalLane = [&](int j) {
        int orig = cidx[b * Kn + j];
        const float* kr = key_ + ((size_t)(b * Kn + orig)) * Hn;
        float d = 0.f;
        for (int h = 0; h < 512; h += 8) {
            f16x8 qh = *(const f16x8*)(qhRow + h);
            f16x8 ql = *(const f16x8*)(qlRow + h);
            f32x4 k0 = *(const f32x4*)(kr + h);
            f32x4 k1 = *(const f32x4*)(kr + h + 4);
            #pragma unroll
            for (int e = 0; e < 4; ++e) {
                d += ((float)qh[e]     + (float)ql[e]     * (1.0f / 2048.0f)) * k0[e];
                d += ((float)qh[e + 4] + (float)ql[e + 4] * (1.0f / 2048.0f)) * k1[e];
            }
        }
        d += beta[b * Kn + j];
        if (d > bestV || (d == bestV && orig < bestOrig)) { bestV = d; bestOrig = orig; }
    };

    // singles (chunk top-1 candidates not needing a full scan): lane-th bit
    unsigned long long singles = candMask & ~scanMask;
    {
        int c2 = 0, myChunk = -1;
        for (int c = 0; c < nch; ++c)
            if ((singles >> c) & 1) { if (c2 == lane) myChunk = c; ++c2; }
        int mc = (myChunk >= 0) ? myChunk : 0;
        int j = __shfl(chi, mc, 64);            // uniform shfl execution
        if (myChunk >= 0) evalLane(j);
    }
    // full-chunk scans: 2 candidates per lane per chunk
    for (int c = 0; c < nch; ++c) {
        if (!((scanMask >> c) & 1)) continue;
        int jend = min(128, cn - c * 128);
        for (int t = lane; t < jend; t += 64) evalLane(c * 128 + t);
    }
    // wave reduce with np tie-break (lowest original index)
    #pragma unroll
    for (int sm = 1; sm < 64; sm <<= 1) {
        float ov = __shfl_xor(bestV, sm, 64);
        int   oo = __shfl_xor(bestOrig, sm, 64);
        if (ov > bestV || (ov == bestV && oo < bestOrig)) { bestV = ov; bestOrig = oo; }
    }
    if (lane == 0) idxArr[m] = bestOrig;
}

// ---------------------------------------------------------------------------
// tail_fused: blocks 0..1023 = res GEMM (value[argmax].NtB + cvec, f32 out);
// blocks 1024.. = score one-hot rows (erases all scratch in score region).
// ---------------------------------------------------------------------------
__global__ __launch_bounds__(256) void tail_fused(
    const float* __restrict__ value, const short* __restrict__ NtB,
    const float* __restrict__ cvec, const int* __restrict__ idxArr,
    float* __restrict__ res, float* __restrict__ score)
{
    __shared__ __align__(16) short As[2][2048], Bs[2][4096];
    const int bid = blockIdx.x;
    const int tid = threadIdx.x, lane = tid & 63, wid = tid >> 6;
    if (bid >= 1024) {
        int m = bid - 1024;
        int c = idxArr[m];
        float* row = score + (size_t)m * Kn;
        #pragma unroll
        for (int i = 0; i < 2; ++i) {
            int v = tid + i * 256;
            f32x4 val = {0.f, 0.f, 0.f, 0.f};
            if ((c >> 2) == v) val[c & 3] = 1.0f;
            *(f32x4*)(row + v * 4) = val;
        }
        return;
    }
    const int l15 = lane & 15, lg = lane >> 4;
    const int m0 = (bid & 255) * 64, n0 = (bid >> 8) * 128;
    const int srow = lane >> 2, sg = lane & 3;
    const int ar0 = tid >> 3, ac0 = (tid & 7) * 4;

    const float* aSrc[2];
    #pragma unroll
    for (int rr = 0; rr < 2; ++rr) {
        int row = ar0 + rr * 32;
        int bb = m0 >> 11;
        aSrc[rr] = value + (size_t)(bb * Kn + idxArr[m0 + row]) * Hn;
    }

    auto stageB = [&](int buf, int ks) {
        const int k0 = ks << 5;
        #pragma unroll
        for (int h = 0; h < 2; ++h) {
            int s = wid + h * 4;
            int row = s * 16 + srow;
            int goff = k0 + ((sg ^ swz(row)) << 3);
            gl_lds16(NtB + (size_t)(n0 + row) * Hn + goff, &Bs[buf][s * 512]);
        }
    };
    auto writeA = [&](int buf, const f32x4* av) {
        #pragma unroll
        for (int rr = 0; rr < 2; ++rr) {
            int row = ar0 + rr * 32;
            s16x4 o;
            #pragma unroll
            for (int j = 0; j < 4; ++j) o[j] = bf16r(av[rr][j]);
            int off = row * 32 + (((ac0 >> 3) ^ swz(row)) << 3) + (ac0 & 7);
            *(s16x4*)&As[buf][off] = o;
        }
    };

    f32x4 acc[4][2] = {};
    {
        f32x4 av[2];
        #pragma unroll
        for (int rr = 0; rr < 2; ++rr) av[rr] = *(const f32x4*)(aSrc[rr] + ac0);
        stageB(0, 0);
        writeA(0, av);
    }
    __syncthreads();
    #pragma unroll 1
    for (int ks = 0; ks < 16; ++ks) {
        const int cur = ks & 1, nxt = cur ^ 1;
        f32x4 av[2];
        if (ks < 15) {
            const int k1 = (ks + 1) << 5;
            #pragma unroll
            for (int rr = 0; rr < 2; ++rr) av[rr] = *(const f32x4*)(aSrc[rr] + k1 + ac0);
            stageB(nxt, ks + 1);
        }
        s16x8 fb[2];
        #pragma unroll
        for (int fj = 0; fj < 2; ++fj) {
            int row = wid * 32 + fj * 16 + l15;
            fb[fj] = *(s16x8*)&Bs[cur][row * 32 + ((lg ^ swz(row)) << 3)];
        }
        #pragma unroll
        for (int fi = 0; fi < 4; ++fi) {
            int row = fi * 16 + l15;
            s16x8 fa = *(s16x8*)&As[cur][row * 32 + ((lg ^ swz(row)) << 3)];
            #pragma unroll
            for (int fj = 0; fj < 2; ++fj)
                acc[fi][fj] = MFMAB16(fa, fb[fj], acc[fi][fj]);
        }
        if (ks < 15) writeA(nxt, av);
        __syncthreads();
    }
    #pragma unroll
    for (int fi = 0; fi < 4; ++fi)
    #pragma unroll
    for (int fj = 0; fj < 2; ++fj)
    #pragma unroll
    for (int j = 0; j < 4; ++j) {
        int m = m0 + fi * 16 + lg * 4 + j;
        int n = n0 + wid * 32 + fj * 16 + l15;
        res[(size_t)m * Hn + n] = acc[fi][fj][j] + cvec[n];
    }
}

// ---------------------------------------------------------------------------
extern "C" void kernel_launch(void* const* d_in, const int* in_sizes, int n_in,
                              void* d_out, int out_size, void* d_ws, size_t ws_size,
                              hipStream_t stream)
{
    const float* query = (const float*)d_in[0];
    const float* key_  = (const float*)d_in[1];
    const float* value = (const float*)d_in[2];
    const int*   mask  = (const int*)d_in[3];
    const float* Wq = (const float*)d_in[4];
    const float* bq = (const float*)d_in[5];
    const float* Wk = (const float*)d_in[6];
    const float* bv = (const float*)d_in[9];
    const float* Wv = (const float*)d_in[8];
    const float* Wo = (const float*)d_in[10];
    const float* bo = (const float*)d_in[11];

    float* res = (float*)d_out;                       // (B,Q,H) f32
    float* scoreBase = res + (size_t)Mn * Hn;         // (B,Q,K) f32, 128 MiB
    char* sc = (char*)scoreBase;                      // scratch inside score region
    constexpr size_t MB = 1u << 20;
    f16*   qM_h = (f16*)(sc + 0 * MB);                // 16 MB
    f16*   qM_l = (f16*)(sc + 16 * MB);               // 16 MB
    f16*   Kc_h = (f16*)(sc + 32 * MB);               // 16 MB
    char*  wb   = sc + 112 * MB;
    f16*   Mt_h = (f16*)(wb);
    f16*   Mt_l = (f16*)(wb + 524288);
    f16*   Wk_h = (f16*)(wb + 2 * 524288);
    f16*   Wk_l = (f16*)(wb + 3 * 524288);
    short* Wot  = (short*)(wb + 4 * 524288);
    float* wvec = (float*)(wb + 5 * 524288);
    float* beta = (float*)(wb + 5 * 524288 + 8192);              // 64 KB
    int*   cidx = (int*)(wb + 5 * 524288 + 8192 + 65536);        // 64 KB
    float* pval1 = (float*)(wb + 6 * 524288);                    // 1 MB
    int*   pidx  = (int*)(wb + 8 * 524288);                      // 1 MB
    float* pval2 = (float*)(wb + 10 * 524288);                   // 1 MB

    int*   idxArr = (int*)d_ws;                                  // 64 KB
    int*   cnt    = (int*)d_ws + 16384;                          // 32 B
    float* cvec   = (float*)((char*)d_ws + 65600);               // 2 KB
    short* NtB    = (short*)((char*)d_ws + 67648);               // 512 KB

    prep_all<<<1033, 256, 0, stream>>>(mask, Wk, Wo, bq, bv, bo,
                                       cidx, cnt, Wk_h, Wk_l, Wot, wvec, cvec);

    gemm_split<1><<<dim3(8, 4), 256, 0, stream>>>(Wq, Wk_h, Wk_l, Mt_h, Mt_l);
    gemm_bfk0<<<dim3(8, 4), 256, 0, stream>>>(Wv, Wot, NtB);

    qm_kconv<<<5120, 256, 0, stream>>>(query, Mt_h, Mt_l, qM_h, qM_l,
                                       key_, cidx, cnt, wvec, Kc_h, beta);

    energy_approx<<<dim3(Qn / 64, 16, Bn), 256, 0, stream>>>(
        qM_h, Kc_h, beta, cnt, pval1, pidx, pval2);

    refine<<<Mn / 4, 256, 0, stream>>>(
        pval1, pidx, pval2, qM_h, qM_l, key_, beta, cidx, cnt, idxArr);

    tail_fused<<<1024 + Mn, 256, 0, stream>>>(value, NtB, cvec, idxArr,
                                              res, scoreBase);
}

// Round 13
// 279.356 us; speedup vs baseline: 1.3923x; 1.0625x over previous
//
#include <hip/hip_runtime.h>

typedef _Float16 f16;
typedef f16 f16x8 __attribute__((ext_vector_type(8)));
typedef f16 f16x4 __attribute__((ext_vector_type(4)));
typedef short s16x8 __attribute__((ext_vector_type(8)));
typedef short s16x4 __attribute__((ext_vector_type(4)));
typedef float f32x4 __attribute__((ext_vector_type(4)));

#define MFMA16(a,b,c)  __builtin_amdgcn_mfma_f32_16x16x32_f16(a,b,c,0,0,0)
#define MFMAB16(a,b,c) __builtin_amdgcn_mfma_f32_16x16x32_bf16(a,b,c,0,0,0)

static constexpr int Bn = 8, Qn = 2048, Kn = 2048, Hn = 512;
static constexpr int Mn = Bn * Qn;           // 16384 flat rows

typedef __attribute__((address_space(1))) const unsigned int as1_uint;
typedef __attribute__((address_space(3))) unsigned int as3_uint;

__device__ __forceinline__ void gl_lds16(const void* g, void* l) {
    __builtin_amdgcn_global_load_lds((as1_uint*)g, (as3_uint*)l, 16, 0, 0);
}

__device__ __forceinline__ short bf16r(float x) {
    unsigned u = __builtin_bit_cast(unsigned, x);
    u += 0x7fffu + ((u >> 16) & 1u);
    return (short)(u >> 16);
}

// swizzle granule: 2-way (free) bank aliasing for ds_read_b128 column reads
__device__ __forceinline__ int swz(int row) { return (row >> 1) & 3; }

// ---------------------------------------------------------------------------
// prep_all: blocks 0..7 compact_mask; 8..1031 Wk x512 split + Wo transpose;
// 1032 bias vectors (wvec true-scale; cvec).
// ---------------------------------------------------------------------------
__global__ __launch_bounds__(256) void prep_all(
    const int* __restrict__ mask, const float* __restrict__ Wk,
    const float* __restrict__ Wo, const float* __restrict__ bq,
    const float* __restrict__ bv, const float* __restrict__ bo,
    int* __restrict__ cidx, int* __restrict__ cnt,
    f16* __restrict__ Wk_h, f16* __restrict__ Wk_l, short* __restrict__ Wot,
    float* __restrict__ wvec, float* __restrict__ cvec)
{
    const int bid = blockIdx.x, t = threadIdx.x;
    if (bid < 8) {
        __shared__ int sums[256];
        int b = bid;
        int base = b * Kn + t * 8;
        int mv[8]; int s = 0;
        #pragma unroll
        for (int i = 0; i < 8; ++i) { mv[i] = (mask[base + i] == 0); s += mv[i]; }
        sums[t] = s;
        __syncthreads();
        for (int off = 1; off < 256; off <<= 1) {
            int v = (t >= off) ? sums[t - off] : 0;
            __syncthreads();
            sums[t] += v;
            __syncthreads();
        }
        int pos = (t > 0 ? sums[t - 1] : 0);
        #pragma unroll
        for (int i = 0; i < 8; ++i)
            if (mv[i]) cidx[b * Kn + pos++] = t * 8 + i;
        if (t == 255) {
            int total = sums[255];
            if (total == 0) { cidx[b * Kn] = 0; total = 1; }
            cnt[b] = total;
        }
    } else if (bid < 1032) {
        int e = (bid - 8) * 256 + t;
        float v = Wk[e] * 512.0f;
        f16 h = (f16)v;
        Wk_h[e] = h; Wk_l[e] = (f16)((v - (float)h) * 2048.0f);
        int r = e >> 9, c = e & 511;
        Wot[c * 512 + r] = bf16r(Wo[e]);
    } else {
        #pragma unroll
        for (int i = 0; i < 2; ++i) {
            int tt = t + i * 256;
            float s = 0.f;
            for (int n = 0; n < 512; n += 4) {
                f32x4 a = *(const f32x4*)(Wk + (size_t)tt * 512 + n);
                f32x4 q = *(const f32x4*)(bq + n);
                s += a[0]*q[0] + a[1]*q[1] + a[2]*q[2] + a[3]*q[3];
            }
            wvec[tt] = s;                       // beta basis, true scale
            float s2 = 0.f;
            for (int h = 0; h < 512; ++h) s2 += bv[h] * Wo[h * 512 + tt];
            cvec[tt] = s2 + bo[tt];
        }
    }
}

// ---------------------------------------------------------------------------
// gemm_G: G = Wq . Wk^T, x512 (B pre-scaled), fp16x2 3-product, split out
// ROW-major [a][b]. Tiny: grid (8,4).
// ---------------------------------------------------------------------------
__global__ __launch_bounds__(256) void gemm_G(
    const float* __restrict__ Af,
    const f16* __restrict__ Bh_g, const f16* __restrict__ Bl_g,
    f16* __restrict__ Oh, f16* __restrict__ Ol)
{
    __shared__ __align__(16) f16 Ah[2][2048], Al[2][2048], Bh[2][4096], Bl[2][4096];
    const int tid = threadIdx.x, lane = tid & 63, wid = tid >> 6;
    const int l15 = lane & 15, lg = lane >> 4;
    const int m0 = blockIdx.x * 64, n0 = blockIdx.y * 128;
    const int srow = lane >> 2, sg = lane & 3;
    const int ar0 = tid >> 3, ac0 = (tid & 7) * 4;

    auto stageB = [&](int buf, int ks) {
        const int k0 = ks << 5;
        #pragma unroll
        for (int h = 0; h < 2; ++h) {
            int s = wid + h * 4;
            int row = s * 16 + srow;
            int goff = k0 + ((sg ^ swz(row)) << 3);
            gl_lds16(Bh_g + (size_t)(n0 + row) * Hn + goff, &Bh[buf][s * 512]);
            gl_lds16(Bl_g + (size_t)(n0 + row) * Hn + goff, &Bl[buf][s * 512]);
        }
    };
    auto writeA = [&](int buf, const f32x4* av) {
        #pragma unroll
        for (int rr = 0; rr < 2; ++rr) {
            int row = ar0 + rr * 32;
            f16x4 oh, ol;
            #pragma unroll
            for (int j = 0; j < 4; ++j) {
                f16 hh = (f16)av[rr][j];
                oh[j] = hh;
                ol[j] = (f16)((av[rr][j] - (float)hh) * 2048.0f);
            }
            int off = row * 32 + (((ac0 >> 3) ^ swz(row)) << 3) + (ac0 & 7);
            *(f16x4*)&Ah[buf][off] = oh;
            *(f16x4*)&Al[buf][off] = ol;
        }
    };

    const float* aSrc[2];
    #pragma unroll
    for (int rr = 0; rr < 2; ++rr)
        aSrc[rr] = Af + (size_t)(m0 + ar0 + rr * 32) * Hn;

    f32x4 a0[4][2] = {}, a1[4][2] = {};
    {
        f32x4 av[2];
        #pragma unroll
        for (int rr = 0; rr < 2; ++rr) av[rr] = *(const f32x4*)(aSrc[rr] + ac0);
        stageB(0, 0);
        writeA(0, av);
    }
    __syncthreads();
    #pragma unroll 1
    for (int ks = 0; ks < 16; ++ks) {
        const int cur = ks & 1, nxt = cur ^ 1;
        f32x4 av[2];
        if (ks < 15) {
            const int k1 = (ks + 1) << 5;
            #pragma unroll
            for (int rr = 0; rr < 2; ++rr) av[rr] = *(const f32x4*)(aSrc[rr] + k1 + ac0);
            stageB(nxt, ks + 1);
        }
        f16x8 fbh[2], fbl[2];
        #pragma unroll
        for (int fj = 0; fj < 2; ++fj) {
            int row = wid * 32 + fj * 16 + l15;
            int off = row * 32 + ((lg ^ swz(row)) << 3);
            fbh[fj] = *(f16x8*)&Bh[cur][off];
            fbl[fj] = *(f16x8*)&Bl[cur][off];
        }
        #pragma unroll
        for (int fi = 0; fi < 4; ++fi) {
            int row = fi * 16 + l15;
            int off = row * 32 + ((lg ^ swz(row)) << 3);
            f16x8 fah = *(f16x8*)&Ah[cur][off];
            f16x8 fal = *(f16x8*)&Al[cur][off];
            #pragma unroll
            for (int fj = 0; fj < 2; ++fj) {
                a0[fi][fj] = MFMA16(fah, fbh[fj], a0[fi][fj]);
                a1[fi][fj] = MFMA16(fah, fbl[fj], a1[fi][fj]);
                a1[fi][fj] = MFMA16(fal, fbh[fj], a1[fi][fj]);
            }
        }
        if (ks < 15) writeA(nxt, av);
        __syncthreads();
    }
    #pragma unroll
    for (int fi = 0; fi < 4; ++fi)
    #pragma unroll
    for (int fj = 0; fj < 2; ++fj)
    #pragma unroll
    for (int j = 0; j < 4; ++j) {
        int m = m0 + fi * 16 + lg * 4 + j;
        int n = n0 + wid * 32 + fj * 16 + l15;
        float v = a0[fi][fj][j] + a1[fi][fj][j] * (1.0f / 2048.0f);   // G x512
        f16 h = (f16)v;
        Oh[(size_t)m * Hn + n] = h;
        Ol[(size_t)m * Hn + n] = (f16)((v - (float)h) * 2048.0f);
    }
}

// ---------------------------------------------------------------------------
// gemm_bfk0: NtB prep — A=Wv rows, out bf16 TRANSPOSED [n][m], no bias.
// ---------------------------------------------------------------------------
__global__ __launch_bounds__(256) void gemm_bfk0(
    const float* __restrict__ Af, const short* __restrict__ Bt,
    short* __restrict__ Out)
{
    __shared__ __align__(16) short As[2][2048], Bs[2][4096];
    const int tid = threadIdx.x, lane = tid & 63, wid = tid >> 6;
    const int l15 = lane & 15, lg = lane >> 4;
    const int m0 = blockIdx.x * 64, n0 = blockIdx.y * 128;
    const int srow = lane >> 2, sg = lane & 3;
    const int ar0 = tid >> 3, ac0 = (tid & 7) * 4;

    const float* aSrc[2];
    #pragma unroll
    for (int rr = 0; rr < 2; ++rr)
        aSrc[rr] = Af + (size_t)(m0 + ar0 + rr * 32) * Hn;

    auto stageB = [&](int buf, int ks) {
        const int k0 = ks << 5;
        #pragma unroll
        for (int h = 0; h < 2; ++h) {
            int s = wid + h * 4;
            int row = s * 16 + srow;
            int goff = k0 + ((sg ^ swz(row)) << 3);
            gl_lds16(Bt + (size_t)(n0 + row) * Hn + goff, &Bs[buf][s * 512]);
        }
    };
    auto writeA = [&](int buf, const f32x4* av) {
        #pragma unroll
        for (int rr = 0; rr < 2; ++rr) {
            int row = ar0 + rr * 32;
            s16x4 o;
            #pragma unroll
            for (int j = 0; j < 4; ++j) o[j] = bf16r(av[rr][j]);
            int off = row * 32 + (((ac0 >> 3) ^ swz(row)) << 3) + (ac0 & 7);
            *(s16x4*)&As[buf][off] = o;
        }
    };

    f32x4 acc[4][2] = {};
    {
        f32x4 av[2];
        #pragma unroll
        for (int rr = 0; rr < 2; ++rr) av[rr] = *(const f32x4*)(aSrc[rr] + ac0);
        stageB(0, 0);
        writeA(0, av);
    }
    __syncthreads();
    #pragma unroll 1
    for (int ks = 0; ks < 16; ++ks) {
        const int cur = ks & 1, nxt = cur ^ 1;
        f32x4 av[2];
        if (ks < 15) {
            const int k1 = (ks + 1) << 5;
            #pragma unroll
            for (int rr = 0; rr < 2; ++rr) av[rr] = *(const f32x4*)(aSrc[rr] + k1 + ac0);
            stageB(nxt, ks + 1);
        }
        s16x8 fb[2];
        #pragma unroll
        for (int fj = 0; fj < 2; ++fj) {
            int row = wid * 32 + fj * 16 + l15;
            fb[fj] = *(s16x8*)&Bs[cur][row * 32 + ((lg ^ swz(row)) << 3)];
        }
        #pragma unroll
        for (int fi = 0; fi < 4; ++fi) {
            int row = fi * 16 + l15;
            s16x8 fa = *(s16x8*)&As[cur][row * 32 + ((lg ^ swz(row)) << 3)];
            #pragma unroll
            for (int fj = 0; fj < 2; ++fj)
                acc[fi][fj] = MFMAB16(fa, fb[fj], acc[fi][fj]);
        }
        if (ks < 15) writeA(nxt, av);
        __syncthreads();
    }
    #pragma unroll
    for (int fi = 0; fi < 4; ++fi)
    #pragma unroll
    for (int fj = 0; fj < 2; ++fj)
    #pragma unroll
    for (int j = 0; j < 4; ++j) {
        int m = m0 + fi * 16 + lg * 4 + j;
        int n = n0 + wid * 32 + fj * 16 + l15;
        Out[(size_t)n * Hn + m] = bf16r(acc[fi][fj][j]);
    }
}

// ---------------------------------------------------------------------------
// kmqb: blocks [0,1024) = kM GEMM over compacted keys (A = gathered raw k
// f32, split on the fly; B = G x512 split; out kM = kG x512 split, compacted
// rows). [1024,5120) = qconv f16 cast of query. [5120,9216) = beta.
// ---------------------------------------------------------------------------
__global__ __launch_bounds__(256) void kmqb(
    const float* __restrict__ key_, const float* __restrict__ query,
    const f16* __restrict__ G_h, const f16* __restrict__ G_l,
    const int* __restrict__ cidx, const int* __restrict__ cnt,
    const float* __restrict__ wvec,
    f16* __restrict__ kM_h, f16* __restrict__ kM_l,
    f16* __restrict__ qf, float* __restrict__ beta)
{
    __shared__ __align__(16) f16 Ah[2][2048], Al[2][2048], Bh[2][4096], Bl[2][4096];
    const int bid = blockIdx.x;
    const int tid = threadIdx.x, lane = tid & 63, wid = tid >> 6;
    if (bid < 1024) {
        const int b = bid >> 7, rem = bid & 127;
        const int m0l = (rem >> 2) * 64, n0 = (rem & 3) * 128;
        const int cn = cnt[b];
        if (m0l >= cn) return;
        const int l15 = lane & 15, lg = lane >> 4;
        const int srow = lane >> 2, sg = lane & 3;
        const int ar0 = tid >> 3, ac0 = (tid & 7) * 4;

        const float* aSrc[2];
        #pragma unroll
        for (int rr = 0; rr < 2; ++rr) {
            int r = m0l + ar0 + rr * 32;
            int cid = (r < cn) ? cidx[b * Kn + r] : 0;
            aSrc[rr] = key_ + (size_t)(b * Kn + cid) * Hn;
        }

        auto stageB = [&](int buf, int ks) {
            const int k0 = ks << 5;
            #pragma unroll
            for (int h = 0; h < 2; ++h) {
                int s = wid + h * 4;
                int row = s * 16 + srow;
                int goff = k0 + ((sg ^ swz(row)) << 3);
                gl_lds16(G_h + (size_t)(n0 + row) * Hn + goff, &Bh[buf][s * 512]);
                gl_lds16(G_l + (size_t)(n0 + row) * Hn + goff, &Bl[buf][s * 512]);
            }
        };
        auto writeA = [&](int buf, const f32x4* av) {
            #pragma unroll
            for (int rr = 0; rr < 2; ++rr) {
                int row = ar0 + rr * 32;
                f16x4 oh, ol;
                #pragma unroll
                for (int j = 0; j < 4; ++j) {
                    f16 hh = (f16)av[rr][j];
                    oh[j] = hh;
                    ol[j] = (f16)((av[rr][j] - (float)hh) * 2048.0f);
                }
                int off = row * 32 + (((ac0 >> 3) ^ swz(row)) << 3) + (ac0 & 7);
                *(f16x4*)&Ah[buf][off] = oh;
                *(f16x4*)&Al[buf][off] = ol;
            }
        };

        f32x4 a0[4][2] = {}, a1[4][2] = {};
        {
            f32x4 av[2];
            #pragma unroll
            for (int rr = 0; rr < 2; ++rr) av[rr] = *(const f32x4*)(aSrc[rr] + ac0);
            stageB(0, 0);
            writeA(0, av);
        }
        __syncthreads();
        #pragma unroll 1
        for (int ks = 0; ks < 16; ++ks) {
            const int cur = ks & 1, nxt = cur ^ 1;
            f32x4 av[2];
            if (ks < 15) {
                const int k1 = (ks + 1) << 5;
                #pragma unroll
                for (int rr = 0; rr < 2; ++rr) av[rr] = *(const f32x4*)(aSrc[rr] + k1 + ac0);
                stageB(nxt, ks + 1);
            }
            f16x8 fbh[2], fbl[2];
            #pragma unroll
            for (int fj = 0; fj < 2; ++fj) {
                int row = wid * 32 + fj * 16 + l15;
                int off = row * 32 + ((lg ^ swz(row)) << 3);
                fbh[fj] = *(f16x8*)&Bh[cur][off];
                fbl[fj] = *(f16x8*)&Bl[cur][off];
            }
            #pragma unroll
            for (int fi = 0; fi < 4; ++fi) {
                int row = fi * 16 + l15;
                int off = row * 32 + ((lg ^ swz(row)) << 3);
                f16x8 fah = *(f16x8*)&Ah[cur][off];
                f16x8 fal = *(f16x8*)&Al[cur][off];
                #pragma unroll
                for (int fj = 0; fj < 2; ++fj) {
                    a0[fi][fj] = MFMA16(fah, fbh[fj], a0[fi][fj]);
                    a1[fi][fj] = MFMA16(fah, fbl[fj], a1[fi][fj]);
                    a1[fi][fj] = MFMA16(fal, fbh[fj], a1[fi][fj]);
                }
            }
            if (ks < 15) writeA(nxt, av);
            __syncthreads();
        }
        #pragma unroll
        for (int fi = 0; fi < 4; ++fi)
        #pragma unroll
        for (int fj = 0; fj < 2; ++fj)
        #pragma unroll
        for (int j = 0; j < 4; ++j) {
            int jr = m0l + fi * 16 + lg * 4 + j;        // compacted row
            int n = n0 + wid * 32 + fj * 16 + l15;
            float v = a0[fi][fj][j] + a1[fi][fj][j] * (1.0f / 2048.0f);  // kG x512
            f16 h = (f16)v;
            kM_h[((size_t)(b * Kn + jr)) * Hn + n] = h;
            kM_l[((size_t)(b * Kn + jr)) * Hn + n] = (f16)((v - (float)h) * 2048.0f);
        }
    } else if (bid < 5120) {
        // qconv: f16 cast of query, one row per wave
        int m = (bid - 1024) * 4 + wid;
        const float* src = query + (size_t)m * Hn + lane * 8;
        f32x4 v0 = *(const f32x4*)(src);
        f32x4 v1 = *(const f32x4*)(src + 4);
        f16x8 o;
        #pragma unroll
        for (int e = 0; e < 4; ++e) { o[e] = (f16)v0[e]; o[e + 4] = (f16)v1[e]; }
        *(f16x8*)(qf + (size_t)m * Hn + lane * 8) = o;
    } else {
        // beta: gathered raw-k dot wvec, one compacted row per wave
        int s = (bid - 5120) * 4 + wid;
        int b = s >> 11, j = s & 2047;
        if (j >= cnt[b]) return;
        const float* src = key_ + (size_t)(b * Kn + cidx[b * Kn + j]) * Hn;
        float acc = 0.f;
        #pragma unroll
        for (int i = 0; i < 2; ++i) {
            int c0 = lane * 8 + i * 4;
            f32x4 v = *(const f32x4*)(src + c0);
            f32x4 w = *(const f32x4*)(wvec + c0);
            acc += v[0]*w[0] + v[1]*w[1] + v[2]*w[2] + v[3]*w[3];
        }
        #pragma unroll
        for (int sm = 1; sm < 64; sm <<= 1) acc += __shfl_xor(acc, sm, 64);
        if (lane == 0) beta[b * Kn + j] = acc;
    }
}

// ---------------------------------------------------------------------------
// energy_approx: f16(q) x kM_h single-product GEMM, 128q x 128k tile,
// 2x2 waves, 32KB LDS. approx_e = acc/512 + beta. Emits per-(row,chunk)
// top-2 stats only: (val1, compacted idx1, val2).
// ---------------------------------------------------------------------------
__global__ __launch_bounds__(256) void energy_approx(
    const f16* __restrict__ qf, const f16* __restrict__ kMh,
    const float* __restrict__ beta, const int* __restrict__ cnt,
    float* __restrict__ pval1, int* __restrict__ pidx, float* __restrict__ pval2)
{
    __shared__ __align__(16) f16 Ah[2][4096], Bh[2][4096];
    const int tid = threadIdx.x, lane = tid & 63, wid = tid >> 6;
    const int wr = wid >> 1, wc = wid & 1, l15 = lane & 15, lg = lane >> 4;
    const int qt = blockIdx.x, kc = blockIdx.y, b = blockIdx.z;
    const int cn = cnt[b];
    const int kbase = kc << 7;
    if (kbase >= cn) return;
    const int m0 = b * Qn + qt * 128;
    const int kr0 = b * Kn + kbase;
    const int srow = lane >> 2, sg = lane & 3;
    const float NEGINF = -__builtin_inff();

    auto stage = [&](int buf, int ks) {
        const int k0 = ks << 5;
        #pragma unroll
        for (int h = 0; h < 2; ++h) {
            int s = wid + h * 4;
            int row = s * 16 + srow;
            int goff = k0 + ((sg ^ swz(row)) << 3);
            gl_lds16(qf  + (size_t)(m0 + row) * Hn + goff, &Ah[buf][s * 512]);
            gl_lds16(kMh + (size_t)(kr0 + row) * Hn + goff, &Bh[buf][s * 512]);
        }
    };

    f32x4 acc[4][4] = {};
    stage(0, 0);
    __syncthreads();
    #pragma unroll 1
    for (int ks = 0; ks < 16; ++ks) {
        const int cur = ks & 1;
        if (ks < 15) stage(cur ^ 1, ks + 1);
        f16x8 fb[4];
        #pragma unroll
        for (int fj = 0; fj < 4; ++fj) {
            int row = wc * 64 + fj * 16 + l15;
            fb[fj] = *(f16x8*)&Bh[cur][row * 32 + ((lg ^ swz(row)) << 3)];
        }
        #pragma unroll
        for (int fi = 0; fi < 4; ++fi) {
            int row = wr * 64 + fi * 16 + l15;
            f16x8 fa = *(f16x8*)&Ah[cur][row * 32 + ((lg ^ swz(row)) << 3)];
            #pragma unroll
            for (int fj = 0; fj < 4; ++fj)
                acc[fi][fj] = MFMA16(fa, fb[fj], acc[fi][fj]);
        }
        __syncthreads();
    }
    float bet[4]; int valid[4];
    #pragma unroll
    for (int fj = 0; fj < 4; ++fj) {
        int lc = wc * 64 + fj * 16 + l15;
        valid[fj] = (kbase + lc < cn);
        bet[fj] = valid[fj] ? beta[b * Kn + kbase + lc] : 0.0f;
    }
    // reuse Ah[0] as cross-wave scratch (K-loop done, barrier passed)
    float (*bw1)[128] = (float(*)[128])((char*)&Ah[0][0]);
    int   (*bi1)[128] = (int(*)[128])((char*)&Ah[0][0] + 1024);
    float (*bw2)[128] = (float(*)[128])((char*)&Ah[0][0] + 2048);
    #pragma unroll
    for (int fi = 0; fi < 4; ++fi)
    #pragma unroll
    for (int j = 0; j < 4; ++j) {
        float t1 = NEGINF, t2 = NEGINF; int ti = 0x7fffffff;
        #pragma unroll
        for (int fj = 0; fj < 4; ++fj) {
            int lc = wc * 64 + fj * 16 + l15;
            float v = valid[fj] ? (acc[fi][fj][j] * (1.0f / 512.0f) + bet[fj]) : NEGINF;
            if (v > t1 || (v == t1 && lc < ti)) { t2 = t1; t1 = v; ti = lc; }
            else t2 = fmaxf(t2, v);
        }
        #pragma unroll
        for (int sm = 1; sm < 16; sm <<= 1) {
            float o1 = __shfl_xor(t1, sm, 64);
            int   oi = __shfl_xor(ti, sm, 64);
            float o2 = __shfl_xor(t2, sm, 64);
            if (o1 > t1 || (o1 == t1 && oi < ti)) { t2 = fmaxf(t1, o2); t1 = o1; ti = oi; }
            else                                  { t2 = fmaxf(t2, o1); }
        }
        if (l15 == 0) {
            int row = wr * 64 + fi * 16 + lg * 4 + j;
            bw1[wc][row] = t1; bi1[wc][row] = ti; bw2[wc][row] = t2;
        }
    }
    __syncthreads();
    if (tid < 128) {
        float t1 = bw1[0][tid]; int ti = bi1[0][tid]; float t2 = bw2[0][tid];
        float o1 = bw1[1][tid]; int oi = bi1[1][tid]; float o2 = bw2[1][tid];
        if (o1 > t1 || (o1 == t1 && oi < ti)) { t2 = fmaxf(t1, o2); t1 = o1; ti = oi; }
        else                                  { t2 = fmaxf(t2, o1); }
        int m = m0 + tid;
        pval1[m * 16 + kc] = t1;
        pidx [m * 16 + kc] = kbase + ti;
        pval2[m * 16 + kc] = t2;
    }
}

// ---------------------------------------------------------------------------
// refine: one wave per q-row, chunk top-2 stats, window 0.35. Fast path:
// single candidate. Slow path: LANE-PARALLEL exact dots — f32 query row
// (pristine input, broadcast) x kM hi/lo reconstruct. np tie-breaking.
// ---------------------------------------------------------------------------
__global__ __launch_bounds__(256) void refine(
    const float* __restrict__ pval1, const int* __restrict__ pidx,
    const float* __restrict__ pval2,
    const float* __restrict__ query,
    const f16* __restrict__ kMh, const f16* __restrict__ kMl,
    const float* __restrict__ beta,
    const int* __restrict__ cidx, const int* __restrict__ cnt,
    int* __restrict__ idxArr)
{
    const int wid = threadIdx.x >> 6, lane = threadIdx.x & 63;
    const int m = blockIdx.x * 4 + wid;
    const int b = m >> 11;
    const int cn = cnt[b];
    const int nch = (cn + 127) >> 7;
    const float NEGINF = -__builtin_inff();

    float chv = (lane < nch) ? pval1[m * 16 + lane] : NEGINF;
    int   chi = (lane < nch) ? pidx [m * 16 + lane] : 0x7fffffff;
    float ch2 = (lane < nch) ? pval2[m * 16 + lane] : NEGINF;

    float gv = chv; int gi = chi;
    #pragma unroll
    for (int sm = 1; sm < 64; sm <<= 1) {
        float ov = __shfl_xor(gv, sm, 64);
        int   oi = __shfl_xor(gi, sm, 64);
        if (ov > gv || (ov == gv && oi < gi)) { gv = ov; gi = oi; }
    }
    const float thr = gv - 0.35f;
    unsigned long long candMask = __ballot(chv >= thr);
    unsigned long long scanMask = __ballot(ch2 >= thr);
    if (__popcll(candMask) == 1 && scanMask == 0ULL) {
        if (lane == 0) idxArr[m] = cidx[b * Kn + gi];
        return;
    }
    const float* qr = query + (size_t)m * Hn;
    float bestV = NEGINF; int bestOrig = 0x7fffffff;

    auto evalLane = [&](int j) {
        const f16* kh = kMh + ((size_t)(b * Kn + j)) * Hn;
        const f16* kl = kMl + ((size_t)(b * Kn + j)) * Hn;
        float d = 0.f;
        for (int h = 0; h < 512; h += 8) {
            f32x4 q0 = *(const f32x4*)(qr + h);
            f32x4 q1 = *(const f32x4*)(qr + h + 4);
            f16x8 vh = *(const f16x8*)(kh + h);
            f16x8 vl = *(const f16x8*)(kl + h);
            #pragma unroll
            for (int e = 0; e < 4; ++e) {
                d += q0[e] * ((float)vh[e]     + (float)vl[e]     * (1.0f / 2048.0f));
                d += q1[e] * ((float)vh[e + 4] + (float)vl[e + 4] * (1.0f / 2048.0f));
            }
        }
        d = d * (1.0f / 512.0f) + beta[b * Kn + j];
        int orig = cidx[b * Kn + j];
        if (d > bestV || (d == bestV && orig < bestOrig)) { bestV = d; bestOrig = orig; }
    };

    // singles (chunk top-1 candidates not needing a full scan)
    unsigned long long singles = candMask & ~scanMask;
    {
        int c2 = 0, myChunk = -1;
        for (int c = 0; c < nch; ++c)
            if ((singles >> c) & 1) { if (c2 == lane) myChunk = c; ++c2; }
        int mc = (myChunk >= 0) ? myChunk : 0;
        int j = __shfl(chi, mc, 64);
        if (myChunk >= 0) evalLane(j);
    }
    // full-chunk scans: 2 candidates per lane per chunk
    for (int c = 0; c < nch; ++c) {
        if (!((scanMask >> c) & 1)) continue;
        int jend = min(128, cn - c * 128);
        for (int t = lane; t < jend; t += 64) evalLane(c * 128 + t);
    }
    #pragma unroll
    for (int sm = 1; sm < 64; sm <<= 1) {
        float ov = __shfl_xor(bestV, sm, 64);
        int   oo = __shfl_xor(bestOrig, sm, 64);
        if (ov > bestV || (ov == bestV && oo < bestOrig)) { bestV = ov; bestOrig = oo; }
    }
    if (lane == 0) idxArr[m] = bestOrig;
}

// ---------------------------------------------------------------------------
// tail_fused: blocks 0..1023 = res GEMM (value[argmax].NtB + cvec, f32 out);
// blocks 1024.. = score one-hot rows (erases all scratch in score region).
// ---------------------------------------------------------------------------
__global__ __launch_bounds__(256) void tail_fused(
    const float* __restrict__ value, const short* __restrict__ NtB,
    const float* __restrict__ cvec, const int* __restrict__ idxArr,
    float* __restrict__ res, float* __restrict__ score)
{
    __shared__ __align__(16) short As[2][2048], Bs[2][4096];
    const int bid = blockIdx.x;
    const int tid = threadIdx.x, lane = tid & 63, wid = tid >> 6;
    if (bid >= 1024) {
        int m = bid - 1024;
        int c = idxArr[m];
        float* row = score + (size_t)m * Kn;
        #pragma unroll
        for (int i = 0; i < 2; ++i) {
            int v = tid + i * 256;
            f32x4 val = {0.f, 0.f, 0.f, 0.f};
            if ((c >> 2) == v) val[c & 3] = 1.0f;
            *(f32x4*)(row + v * 4) = val;
        }
        return;
    }
    const int l15 = lane & 15, lg = lane >> 4;
    const int m0 = (bid & 255) * 64, n0 = (bid >> 8) * 128;
    const int srow = lane >> 2, sg = lane & 3;
    const int ar0 = tid >> 3, ac0 = (tid & 7) * 4;

    const float* aSrc[2];
    #pragma unroll
    for (int rr = 0; rr < 2; ++rr) {
        int row = ar0 + rr * 32;
        int bb = m0 >> 11;
        aSrc[rr] = value + (size_t)(bb * Kn + idxArr[m0 + row]) * Hn;
    }

    auto stageB = [&](int buf, int ks) {
        const int k0 = ks << 5;
        #pragma unroll
        for (int h = 0; h < 2; ++h) {
            int s = wid + h * 4;
            int row = s * 16 + srow;
            int goff = k0 + ((sg ^ swz(row)) << 3);
            gl_lds16(NtB + (size_t)(n0 + row) * Hn + goff, &Bs[buf][s * 512]);
        }
    };
    auto writeA = [&](int buf, const f32x4* av) {
        #pragma unroll
        for (int rr = 0; rr < 2; ++rr) {
            int row = ar0 + rr * 32;
            s16x4 o;
            #pragma unroll
            for (int j = 0; j < 4; ++j) o[j] = bf16r(av[rr][j]);
            int off = row * 32 + (((ac0 >> 3) ^ swz(row)) << 3) + (ac0 & 7);
            *(s16x4*)&As[buf][off] = o;
        }
    };

    f32x4 acc[4][2] = {};
    {
        f32x4 av[2];
        #pragma unroll
        for (int rr = 0; rr < 2; ++rr) av[rr] = *(const f32x4*)(aSrc[rr] + ac0);
        stageB(0, 0);
        writeA(0, av);
    }
    __syncthreads();
    #pragma unroll 1
    for (int ks = 0; ks < 16; ++ks) {
        const int cur = ks & 1, nxt = cur ^ 1;
        f32x4 av[2];
        if (ks < 15) {
            const int k1 = (ks + 1) << 5;
            #pragma unroll
            for (int rr = 0; rr < 2; ++rr) av[rr] = *(const f32x4*)(aSrc[rr] + k1 + ac0);
            stageB(nxt, ks + 1);
        }
        s16x8 fb[2];
        #pragma unroll
        for (int fj = 0; fj < 2; ++fj) {
            int row = wid * 32 + fj * 16 + l15;
            fb[fj] = *(s16x8*)&Bs[cur][row * 32 + ((lg ^ swz(row)) << 3)];
        }
        #pragma unroll
        for (int fi = 0; fi < 4; ++fi) {
            int row = fi * 16 + l15;
            s16x8 fa = *(s16x8*)&As[cur][row * 32 + ((lg ^ swz(row)) << 3)];
            #pragma unroll
            for (int fj = 0; fj < 2; ++fj)
                acc[fi][fj] = MFMAB16(fa, fb[fj], acc[fi][fj]);
        }
        if (ks < 15) writeA(nxt, av);
        __syncthreads();
    }
    #pragma unroll
    for (int fi = 0; fi < 4; ++fi)
    #pragma unroll
    for (int fj = 0; fj < 2; ++fj)
    #pragma unroll
    for (int j = 0; j < 4; ++j) {
        int m = m0 + fi * 16 + lg * 4 + j;
        int n = n0 + wid * 32 + fj * 16 + l15;
        res[(size_t)m * Hn + n] = acc[fi][fj][j] + cvec[n];
    }
}

// ---------------------------------------------------------------------------
extern "C" void kernel_launch(void* const* d_in, const int* in_sizes, int n_in,
                              void* d_out, int out_size, void* d_ws, size_t ws_size,
                              hipStream_t stream)
{
    const float* query = (const float*)d_in[0];
    const float* key_  = (const float*)d_in[1];
    const float* value = (const float*)d_in[2];
    const int*   mask  = (const int*)d_in[3];
    const float* Wq = (const float*)d_in[4];
    const float* bq = (const float*)d_in[5];
    const float* Wk = (const float*)d_in[6];
    const float* bv = (const float*)d_in[9];
    const float* Wv = (const float*)d_in[8];
    const float* Wo = (const float*)d_in[10];
    const float* bo = (const float*)d_in[11];

    float* res = (float*)d_out;                       // (B,Q,H) f32
    float* scoreBase = res + (size_t)Mn * Hn;         // (B,Q,K) f32, 128 MiB
    char* sc = (char*)scoreBase;                      // scratch inside score region
    constexpr size_t MB = 1u << 20;
    f16*   qf   = (f16*)(sc + 0 * MB);                // 16 MB
    f16*   kM_h = (f16*)(sc + 16 * MB);               // 16 MB
    f16*   kM_l = (f16*)(sc + 32 * MB);               // 16 MB
    char*  wb   = sc + 112 * MB;
    f16*   G_h  = (f16*)(wb);
    f16*   G_l  = (f16*)(wb + 524288);
    f16*   Wk_h = (f16*)(wb + 2 * 524288);
    f16*   Wk_l = (f16*)(wb + 3 * 524288);
    short* Wot  = (short*)(wb + 4 * 524288);
    float* wvec = (float*)(wb + 5 * 524288);
    float* beta = (float*)(wb + 5 * 524288 + 8192);              // 64 KB
    int*   cidx = (int*)(wb + 5 * 524288 + 8192 + 65536);        // 64 KB
    float* pval1 = (float*)(wb + 6 * 524288);                    // 1 MB
    int*   pidx  = (int*)(wb + 8 * 524288);                      // 1 MB
    float* pval2 = (float*)(wb + 10 * 524288);                   // 1 MB

    int*   idxArr = (int*)d_ws;                                  // 64 KB
    int*   cnt    = (int*)d_ws + 16384;                          // 32 B
    float* cvec   = (float*)((char*)d_ws + 65600);               // 2 KB
    short* NtB    = (short*)((char*)d_ws + 67648);               // 512 KB

    prep_all<<<1033, 256, 0, stream>>>(mask, Wk, Wo, bq, bv, bo,
                                       cidx, cnt, Wk_h, Wk_l, Wot, wvec, cvec);

    gemm_G<<<dim3(8, 4), 256, 0, stream>>>(Wq, Wk_h, Wk_l, G_h, G_l);
    gemm_bfk0<<<dim3(8, 4), 256, 0, stream>>>(Wv, Wot, NtB);

    kmqb<<<9216, 256, 0, stream>>>(key_, query, G_h, G_l, cidx, cnt, wvec,
                                   kM_h, kM_l, qf, beta);

    energy_approx<<<dim3(Qn / 128, 16, Bn), 256, 0, stream>>>(
        qf, kM_h, beta, cnt, pval1, pidx, pval2);

    refine<<<Mn / 4, 256, 0, stream>>>(
        pval1, pidx, pval2, query, kM_h, kM_l, beta, cidx, cnt, idxArr);

    tail_fused<<<1024 + Mn, 256, 0, stream>>>(value, NtB, cvec, idxArr,
                                              res, scoreBase);
}